// Round 5
// baseline (1534.723 us; speedup 1.0000x reference)
//
#include <hip/hip_runtime.h>
#include <hip/hip_bf16.h>
#include <stdint.h>

#define BB 16
#define TMAX 30
#define FEAT 512
#define RNN 512
#define ATTN 512
#define VOCABP1 111
#define HH 8
#define WW 64
#define HWD 512
#define PH 10
#define PW 66
#define PROWS 660
#define G4 2048
#define TG 5

typedef unsigned short u16;

__device__ __forceinline__ float fsig(float x){ return 1.0f/(1.0f + __expf(-x)); }
__device__ __forceinline__ float ftanhf(float x){ float e = __expf(2.0f*x); return 1.0f - 2.0f/(e + 1.0f); }

// ---------- features [B,C,H,W] fp32 -> padded fp32 [B, PROWS, C] ----------
__global__ __launch_bounds__(256) void k_tfeat(const float* __restrict__ feats, float* __restrict__ featsPf){
  __shared__ float tile[64*65];
  int b = blockIdx.z, c0 = blockIdx.y*64, hw0 = blockIdx.x*64;
  int tid = threadIdx.x;
  int tx = tid & 63, ty = tid >> 6;
#pragma unroll
  for (int r = 0; r < 16; ++r){
    int cl = ty*16 + r;
    tile[cl*65 + tx] = feats[((size_t)(b*FEAT + c0 + cl))*HWD + hw0 + tx];
  }
  __syncthreads();
#pragma unroll
  for (int r = 0; r < 16; ++r){
    int hwl = ty*16 + r;
    int hw = hw0 + hwl;
    int rowP = hw + 2*(hw >> 6) + 67;   // (y+1)*66 + (x+1)
    featsPf[((size_t)b*PROWS + rowP)*FEAT + c0 + tx] = tile[tx*65 + hwl];
  }
}

// ---------- conv weights [O,C,3,3] fp32 -> fp32 wBf[k9][c][n] ----------
__global__ __launch_bounds__(256) void k_twt(const float* __restrict__ w, float* __restrict__ wBf){
  int idx = blockIdx.x*256 + threadIdx.x;
  if (idx >= 9*512*512) return;
  int n = idx & 511; int c = (idx >> 9) & 511; int k9 = idx >> 18;
  wBf[idx] = w[((size_t)(n*512 + c))*9 + k9];
}

// ---------- conv as implicit-im2col fp32 VALU GEMM (correctness-first) ----------
// C[8192 x 512] = A[8192 x 4608] * W[4608 x 512]; 64x64 tile, BK=32, 4x4/thread
__global__ __launch_bounds__(256) void k_conv32(const float* __restrict__ featsPf, const float* __restrict__ wBf,
                                                const float* __restrict__ bias, float* __restrict__ fp){
  __shared__ float As[64][36];   // stride 36 floats: 16B-aligned rows
  __shared__ float Bs[32][64];
  int m0 = blockIdx.x * 64, n0 = blockIdx.y * 64;
  int tid = threadIdx.x;
  int tm = tid >> 4, tn = tid & 15;

  float acc[4][4];
#pragma unroll
  for (int i=0;i<4;++i)
#pragma unroll
    for (int j=0;j<4;++j) acc[i][j] = 0.f;

  int sArow = tid >> 2, sAk = (tid & 3)*8;    // 64 rows x 32 k, 8 floats/thread
  int mA = m0 + sArow;
  long baseA = ((long)((mA >> 9)*PH + ((mA >> 6) & 7) + 1)*PW + (mA & 63) + 1)*FEAT + sAk;
  int sBk = tid >> 3, sBn = (tid & 7)*8;      // 32 k x 64 n, 8 floats/thread

  for (int ks = 0; ks < 144; ++ks){
    int o = ks >> 4;
    int c0 = (ks & 15) << 5;
    int dy = o/3 - 1, dx = o - (o/3)*3 - 1;
    const float* pa = featsPf + baseA + (long)(dy*PW + dx)*FEAT + c0;
    const float* pb = wBf + (long)o*(512*512) + (long)(c0 + sBk)*512 + n0 + sBn;
    __syncthreads();
    *(float4*)&As[sArow][sAk]   = *(const float4*)pa;
    *(float4*)&As[sArow][sAk+4] = *(const float4*)(pa+4);
    *(float4*)&Bs[sBk][sBn]     = *(const float4*)pb;
    *(float4*)&Bs[sBk][sBn+4]   = *(const float4*)(pb+4);
    __syncthreads();
#pragma unroll 8
    for (int k = 0; k < 32; ++k){
      float4 bv = *(const float4*)&Bs[k][tn*4];
      float av0 = As[tm*4+0][k], av1 = As[tm*4+1][k], av2 = As[tm*4+2][k], av3 = As[tm*4+3][k];
      acc[0][0] += av0*bv.x; acc[0][1] += av0*bv.y; acc[0][2] += av0*bv.z; acc[0][3] += av0*bv.w;
      acc[1][0] += av1*bv.x; acc[1][1] += av1*bv.y; acc[1][2] += av1*bv.z; acc[1][3] += av1*bv.w;
      acc[2][0] += av2*bv.x; acc[2][1] += av2*bv.y; acc[2][2] += av2*bv.z; acc[2][3] += av2*bv.w;
      acc[3][0] += av3*bv.x; acc[3][1] += av3*bv.y; acc[3][2] += av3*bv.z; acc[3][3] += av3*bv.w;
    }
  }
#pragma unroll
  for (int mi=0; mi<4; ++mi){
    int gm = m0 + tm*4 + mi;
#pragma unroll
    for (int ni=0; ni<4; ++ni){
      int gn = n0 + tn*4 + ni;
      fp[(size_t)gm*ATTN + gn] = acc[mi][ni] + bias[gn];
    }
  }
}

// ---------- decoder LSTM (h=0, c=0): h0,c0 (fp32) ----------
__global__ __launch_bounds__(512) void k_dec(const float* __restrict__ encoded, const float* __restrict__ Wih,
                                             const float* __restrict__ bih, const float* __restrict__ bhh,
                                             float* __restrict__ h0, float* __restrict__ c0){
  __shared__ float enc[RNN];
  int b = blockIdx.x, u = threadIdx.x;
  enc[u] = encoded[b*RNN + u];
  __syncthreads();
  float acc[4] = {0.f,0.f,0.f,0.f};
  for (int k = 0; k < RNN; k += 4){
#pragma unroll
    for (int gi=0; gi<4; ++gi){
      float4 wv = *(const float4*)&Wih[(size_t)(u + 512*gi)*RNN + k];
      acc[gi] += wv.x*enc[k] + wv.y*enc[k+1] + wv.z*enc[k+2] + wv.w*enc[k+3];
    }
  }
  float gi_ = acc[0] + bih[u]      + bhh[u];
  float gg  = acc[2] + bih[u+1024] + bhh[u+1024];
  float go  = acc[3] + bih[u+1536] + bhh[u+1536];
  float cv = fsig(gi_)*ftanhf(gg);           // f-gate term * c(=0)
  float hv = fsig(go)*ftanhf(cv);
  h0[b*RNN+u] = hv; c0[b*RNN+u] = cv;
}

// ---------- hoisted t-independent gate halves ----------
__global__ __launch_bounds__(512) void k_pre(const float* __restrict__ h0,
                                             const float* __restrict__ Wih, const float* __restrict__ Whh,
                                             const float* __restrict__ bih, const float* __restrict__ bhh,
                                             float* __restrict__ g1h, float* __restrict__ g2x){
  __shared__ float h[RNN];
  int b = blockIdx.x, u = threadIdx.x;
  h[u] = h0[b*RNN+u];
  __syncthreads();
  float a1[4] = {0.f,0.f,0.f,0.f}, a2[4] = {0.f,0.f,0.f,0.f};
  for (int k=0;k<RNN;k+=4){
#pragma unroll
    for (int gi=0; gi<4; ++gi){
      float4 w1 = *(const float4*)&Whh[(size_t)(u+512*gi)*RNN + k];
      a1[gi] += w1.x*h[k] + w1.y*h[k+1] + w1.z*h[k+2] + w1.w*h[k+3];
      float4 w2 = *(const float4*)&Wih[(size_t)(u+512*gi)*RNN + k];
      a2[gi] += w2.x*h[k] + w2.y*h[k+1] + w2.z*h[k+2] + w2.w*h[k+3];
    }
  }
#pragma unroll
  for (int gi=0; gi<4; ++gi){
    float bbv = bih[u+512*gi] + bhh[u+512*gi];
    g1h[b*G4 + u + 512*gi] = a1[gi] + bbv;   // h0@Whh.T + bih + bhh
    g2x[b*G4 + u + 512*gi] = a2[gi] + bbv;   // h0@Wih.T + bih + bhh
  }
}

// ---------- per-(b, t-group) attention LSTM chain + state projection ----------
__global__ __launch_bounds__(512) void k_att(const int* __restrict__ gt, const float* __restrict__ embw,
                                             const float* __restrict__ c0,
                                             const float* __restrict__ g1h, const float* __restrict__ g2x,
                                             const float* __restrict__ Wih, const float* __restrict__ Whh,
                                             const float* __restrict__ scw, float* __restrict__ sp){
  __shared__ float xs[TG][RNN];
  __shared__ float h1s[TG][RNN], c1s[TG][RNN], h2s[TG][RNN];
  int b = blockIdx.x / (TMAX/TG);
  int t0 = (blockIdx.x % (TMAX/TG)) * TG;
  int u = threadIdx.x;
#pragma unroll
  for (int tt=0; tt<TG; ++tt){
    int tok = gt[b*TMAX + t0 + tt];
    xs[tt][u] = embw[(size_t)tok*RNN + u];
  }
  __syncthreads();
  float acc[4][TG];
#pragma unroll
  for (int gi=0;gi<4;++gi)
#pragma unroll
    for (int tt=0;tt<TG;++tt) acc[gi][tt] = 0.f;
  for (int k=0;k<RNN;k+=4){
#pragma unroll
    for (int gi=0;gi<4;++gi){
      float4 wv = *(const float4*)&Wih[(size_t)(u+512*gi)*RNN+k];
#pragma unroll
      for (int tt=0;tt<TG;++tt)
        acc[gi][tt] += wv.x*xs[tt][k] + wv.y*xs[tt][k+1] + wv.z*xs[tt][k+2] + wv.w*xs[tt][k+3];
    }
  }
  float c0v = c0[b*RNN+u];
  float b1i = g1h[b*G4+u], b1f = g1h[b*G4+u+512], b1g = g1h[b*G4+u+1024], b1o = g1h[b*G4+u+1536];
#pragma unroll
  for (int tt=0;tt<TG;++tt){
    float cv = fsig(acc[1][tt]+b1f)*c0v + fsig(acc[0][tt]+b1i)*ftanhf(acc[2][tt]+b1g);
    float hv = fsig(acc[3][tt]+b1o)*ftanhf(cv);
    h1s[tt][u] = hv; c1s[tt][u] = cv;
  }
  __syncthreads();
#pragma unroll
  for (int gi=0;gi<4;++gi)
#pragma unroll
    for (int tt=0;tt<TG;++tt) acc[gi][tt] = 0.f;
  for (int k=0;k<RNN;k+=4){
#pragma unroll
    for (int gi=0;gi<4;++gi){
      float4 wv = *(const float4*)&Whh[(size_t)(u+512*gi)*RNN+k];
#pragma unroll
      for (int tt=0;tt<TG;++tt)
        acc[gi][tt] += wv.x*h1s[tt][k] + wv.y*h1s[tt][k+1] + wv.z*h1s[tt][k+2] + wv.w*h1s[tt][k+3];
    }
  }
  float b2i = g2x[b*G4+u], b2ff = g2x[b*G4+u+512], b2g = g2x[b*G4+u+1024], b2o = g2x[b*G4+u+1536];
  __syncthreads();
#pragma unroll
  for (int tt=0;tt<TG;++tt){
    float cv = fsig(acc[1][tt]+b2ff)*c1s[tt][u] + fsig(acc[0][tt]+b2i)*ftanhf(acc[2][tt]+b2g);
    float hv = fsig(acc[3][tt]+b2o)*ftanhf(cv);
    h2s[tt][u] = hv;
  }
  __syncthreads();
  float sacc[TG];
#pragma unroll
  for (int tt=0;tt<TG;++tt) sacc[tt] = 0.f;
  for (int k=0;k<RNN;k+=4){
    float4 wv = *(const float4*)&scw[(size_t)u*RNN+k];
#pragma unroll
    for (int tt=0;tt<TG;++tt)
      sacc[tt] += wv.x*h2s[tt][k] + wv.y*h2s[tt][k+1] + wv.z*h2s[tt][k+2] + wv.w*h2s[tt][k+3];
  }
#pragma unroll
  for (int tt=0;tt<TG;++tt) sp[((size_t)b*TMAX + t0+tt)*ATTN + u] = sacc[tt];
}

// ---------- scores + softmax ----------
__global__ __launch_bounds__(256) void k_scores(const float* __restrict__ fp, const float* __restrict__ sp,
                                                const float* __restrict__ apw, float* __restrict__ attn){
  __shared__ float sps[ATTN], was[ATTN], sc[HWD], red[256];
  int bt = blockIdx.x, b = bt / TMAX;
  int tid = threadIdx.x;
  sps[tid]     = sp[(size_t)bt*ATTN + tid];
  sps[tid+256] = sp[(size_t)bt*ATTN + tid + 256];
  was[tid]     = apw[tid];
  was[tid+256] = apw[tid + 256];
  __syncthreads();
  const float* fpb = fp + (size_t)b*HWD*ATTN;
  int lane = tid & 63, wave = tid >> 6;
  for (int hw = wave; hw < HWD; hw += 4){
    const float* row = fpb + (size_t)hw*ATTN;
    float s = 0.f;
#pragma unroll
    for (int a0 = 0; a0 < ATTN; a0 += 64){
      int a = a0 + lane;
      s += was[a] * ftanhf(row[a] + sps[a]);
    }
#pragma unroll
    for (int off = 32; off; off >>= 1) s += __shfl_xor(s, off);
    if (lane == 0) sc[hw] = s;
  }
  __syncthreads();
  float v0 = sc[tid], v1 = sc[tid+256];
  red[tid] = fmaxf(v0, v1); __syncthreads();
  for (int sd=128; sd; sd>>=1){ if (tid < sd) red[tid] = fmaxf(red[tid], red[tid+sd]); __syncthreads(); }
  float mx = red[0]; __syncthreads();
  float e0 = __expf(v0-mx), e1 = __expf(v1-mx);
  red[tid] = e0+e1; __syncthreads();
  for (int sd=128; sd; sd>>=1){ if (tid < sd) red[tid] += red[tid+sd]; __syncthreads(); }
  float inv = 1.0f / red[0];
  attn[(size_t)bt*HWD + tid]     = e0*inv;
  attn[(size_t)bt*HWD + tid+256] = e1*inv;
}

// ---------- glimpse + output logits (fp32 output!) ----------
__global__ __launch_bounds__(512) void k_out(const float* __restrict__ attn, const float* __restrict__ featsPf,
                                             const float* __restrict__ outw, const float* __restrict__ outb,
                                             float* __restrict__ out){
  __shared__ float at[HWD];
  __shared__ float gl[FEAT];
  int bt = blockIdx.x, b = bt / TMAX;
  int tid = threadIdx.x;
  at[tid] = attn[(size_t)bt*HWD + tid];
  __syncthreads();
  const float* fb = featsPf + (size_t)b*PROWS*FEAT;
  float g = 0.f;
  for (int hw = 0; hw < HWD; ++hw){
    int rowP = hw + 2*(hw>>6) + 67;
    g += at[hw] * fb[(size_t)rowP*FEAT + tid];
  }
  gl[tid] = g;
  __syncthreads();
  if (tid < VOCABP1){
    float s = outb[tid];
    for (int k=0;k<FEAT;k+=4){
      float4 wv = *(const float4*)&outw[(size_t)tid*FEAT+k];
      s += wv.x*gl[k] + wv.y*gl[k+1] + wv.z*gl[k+2] + wv.w*gl[k+3];
    }
    out[(size_t)bt*VOCABP1 + tid] = s;
  }
}

extern "C" void kernel_launch(void* const* d_in, const int* in_sizes, int n_in,
                              void* d_out, int out_size, void* d_ws, size_t ws_size,
                              hipStream_t stream){
  (void)in_sizes; (void)n_in; (void)out_size; (void)ws_size;
  const float* features = (const float*)d_in[0];
  const float* encoded  = (const float*)d_in[1];
  const float* embed_w  = (const float*)d_in[2];
  const float* dec_Wih  = (const float*)d_in[3];
  const float* dec_bih  = (const float*)d_in[5];
  const float* dec_bhh  = (const float*)d_in[6];
  const float* att_Wih  = (const float*)d_in[7];
  const float* att_Whh  = (const float*)d_in[8];
  const float* att_bih  = (const float*)d_in[9];
  const float* att_bhh  = (const float*)d_in[10];
  const float* fconv_w  = (const float*)d_in[11];
  const float* fconv_b  = (const float*)d_in[12];
  const float* scw      = (const float*)d_in[13];
  const float* apw      = (const float*)d_in[14];
  const float* outw     = (const float*)d_in[15];
  const float* outb     = (const float*)d_in[16];
  const int* gt         = (const int*)d_in[17];

  char* ws = (char*)d_ws;
  float* featsPf = (float*)(ws + 0);           // 16*660*512*4 = 21,626,880
  float* wBf     = (float*)(ws + 21626880);    // 9*512*512*4  =  9,437,184
  float* fp      = (float*)(ws + 31064064);    // 8192*512*4   = 16,777,216
  float* h0      = (float*)(ws + 47841280);    // 32,768
  float* c0      = (float*)(ws + 47874048);    // 32,768
  float* g1h     = (float*)(ws + 47906816);    // 131,072
  float* g2x     = (float*)(ws + 48037888);    // 131,072
  float* sp      = (float*)(ws + 48168960);    // 983,040
  float* attn    = (float*)(ws + 49152000);    // 983,040 -> total 50,135,040 B

  hipMemsetAsync(featsPf, 0, 21626880, stream);
  k_tfeat<<<dim3(8,8,16), 256, 0, stream>>>(features, featsPf);
  k_twt<<<dim3(9216), 256, 0, stream>>>(fconv_w, wBf);
  k_conv32<<<dim3(128,8), 256, 0, stream>>>(featsPf, wBf, fconv_b, fp);
  k_dec<<<dim3(16), 512, 0, stream>>>(encoded, dec_Wih, dec_bih, dec_bhh, h0, c0);
  k_pre<<<dim3(16), 512, 0, stream>>>(h0, att_Wih, att_Whh, att_bih, att_bhh, g1h, g2x);
  k_att<<<dim3(96), 512, 0, stream>>>(gt, embed_w, c0, g1h, g2x, att_Wih, att_Whh, scw, sp);
  k_scores<<<dim3(480), 256, 0, stream>>>(fp, sp, apw, attn);
  k_out<<<dim3(480), 512, 0, stream>>>(attn, featsPf, outw, outb, (float*)d_out);
}

// Round 6
// 527.641 us; speedup vs baseline: 2.9086x; 2.9086x over previous
//
#include <hip/hip_runtime.h>
#include <hip/hip_bf16.h>
#include <stdint.h>

#define BB 16
#define TMAX 30
#define FEAT 512
#define RNN 512
#define ATTN 512
#define VOCABP1 111
#define HWD 512
#define PH 10
#define PW 66
#define PROWS 660
#define G4 2048

typedef unsigned short u16;
typedef __attribute__((ext_vector_type(8))) unsigned short us8v;
typedef __attribute__((ext_vector_type(8))) short short8;
typedef __attribute__((ext_vector_type(4))) float f32x4;

__device__ __forceinline__ u16 f2b(float x){   // RNE
  unsigned int u = __builtin_bit_cast(unsigned int, x);
  unsigned int r = u + 0x7FFFu + ((u >> 16) & 1u);
  return (u16)(r >> 16);
}
__device__ __forceinline__ float fsig(float x){ return 1.0f/(1.0f + __expf(-x)); }
__device__ __forceinline__ float ftanhf(float x){ float e = __expf(2.0f*x); return 1.0f - 2.0f/(e + 1.0f); }

// ---------- features [B,C,HW] fp32 -> padded bf16 [B, PROWS, C] ----------
__global__ __launch_bounds__(256) void k_tfeat(const float* __restrict__ feats, u16* __restrict__ featsP){
  __shared__ float tile[64*65];
  int b = blockIdx.z, c0 = blockIdx.y*64, hw0 = blockIdx.x*64;
  int tid = threadIdx.x;
  int tx = tid & 63, ty = tid >> 6;
#pragma unroll
  for (int r = 0; r < 16; ++r){
    int cl = ty*16 + r;
    tile[cl*65 + tx] = feats[((size_t)(b*FEAT + c0 + cl))*HWD + hw0 + tx];
  }
  __syncthreads();
#pragma unroll
  for (int r = 0; r < 16; ++r){
    int hwl = ty*16 + r;
    int hw = hw0 + hwl;
    int rowP = hw + 2*(hw >> 6) + 67;   // (y+1)*66 + (x+1)
    featsP[((size_t)b*PROWS + rowP)*FEAT + c0 + tx] = f2b(tile[tx*65 + hwl]);
  }
}

// ---------- conv weights [O,C,3,3] fp32 -> bf16 wB[k9][o][c] ----------
__global__ __launch_bounds__(256) void k_twt(const float* __restrict__ w, u16* __restrict__ wB){
  int idx = blockIdx.x*256 + threadIdx.x;
  if (idx >= 9*512*512) return;
  int c = idx & 511; int n = (idx >> 9) & 511; int k9 = idx >> 18;
  wB[idx] = f2b(w[((size_t)(n*512 + c))*9 + k9]);
}

// ---------- conv as implicit-im2col MFMA bf16 GEMM (register staging) ----------
__global__ __launch_bounds__(256) void k_conv(const u16* __restrict__ featsP, const u16* __restrict__ wB,
                                              const float* __restrict__ bias, float* __restrict__ fp){
  __shared__ __align__(16) u16 As[128*32];
  __shared__ __align__(16) u16 Bs[64*32];
  int m0 = blockIdx.x * 128, n0 = blockIdx.y * 64;
  int tid = threadIdx.x, lane = tid & 63, wave = tid >> 6;
  int wm = wave >> 1, wn = wave & 1;

  int kk = (lane & 3) * 8;
  int rA0 = 32*wave + (lane >> 2);
  int rA1 = rA0 + 16;
  int mA0 = m0 + rA0, mA1 = m0 + rA1;
  long baseA0 = ((long)((mA0 >> 9)*PH + ((mA0 >> 6) & 7) + 1)*PW + (mA0 & 63) + 1)*FEAT + kk;
  long baseA1 = ((long)((mA1 >> 9)*PH + ((mA1 >> 6) & 7) + 1)*PW + (mA1 & 63) + 1)*FEAT + kk;
  int nloc = 16*wave + (lane >> 2);
  long baseB = (long)(n0 + nloc)*512 + kk;

  f32x4 acc[4][2];
#pragma unroll
  for (int i=0;i<4;++i)
#pragma unroll
    for (int j=0;j<2;++j) acc[i][j] = (f32x4){0.f,0.f,0.f,0.f};

  int arow = wm*64 + (lane & 15);
  int akc  = (lane >> 4) * 8;
  int brow = wn*32 + (lane & 15);

  us8v a0c, a1c, bc;
  {
    long dA = (long)(-1*PW - 1)*FEAT;   // ks=0: o=0 -> dy=-1,dx=-1,c0=0
    a0c = *(const us8v*)(featsP + baseA0 + dA);
    a1c = *(const us8v*)(featsP + baseA1 + dA);
    bc  = *(const us8v*)(wB + baseB);
  }

  for (int ks = 0; ks < 144; ++ks){
    __syncthreads();
    *(us8v*)&As[rA0*32 + kk] = a0c;
    *(us8v*)&As[rA1*32 + kk] = a1c;
    *(us8v*)&Bs[nloc*32 + kk] = bc;
    __syncthreads();
    if (ks < 143){
      int kn = ks + 1;
      int o = kn >> 4;
      int c0 = (kn & 15) << 5;
      int dy = o/3 - 1, dx = o - (o/3)*3 - 1;
      long dA = (long)(dy*PW + dx)*FEAT + c0;
      long dB = (long)o*(512*512) + c0;
      a0c = *(const us8v*)(featsP + baseA0 + dA);
      a1c = *(const us8v*)(featsP + baseA1 + dA);
      bc  = *(const us8v*)(wB + baseB + dB);
    }
    short8 a[4], bfr[2];
#pragma unroll
    for (int mt=0; mt<4; ++mt) a[mt] = *(const short8*)&As[(arow + mt*16)*32 + akc];
#pragma unroll
    for (int nt=0; nt<2; ++nt) bfr[nt] = *(const short8*)&Bs[(brow + nt*16)*32 + akc];
#pragma unroll
    for (int mt=0; mt<4; ++mt)
#pragma unroll
      for (int nt=0; nt<2; ++nt)
        acc[mt][nt] = __builtin_amdgcn_mfma_f32_16x16x32_bf16(a[mt], bfr[nt], acc[mt][nt], 0, 0, 0);
  }
  int col = lane & 15;
  int rbase = (lane >> 4) * 4;
#pragma unroll
  for (int mt=0; mt<4; ++mt){
#pragma unroll
    for (int nt=0; nt<2; ++nt){
      int gn = n0 + wn*32 + nt*16 + col;
      float bv = bias[gn];
#pragma unroll
      for (int r=0; r<4; ++r){
        int gm = m0 + wm*64 + mt*16 + rbase + r;
        fp[(size_t)gm*ATTN + gn] = acc[mt][nt][r] + bv;
      }
    }
  }
}

// ---------- decoder gates GEMM: Gd[16][2048] ----------
__global__ __launch_bounds__(256) void k_dec_gemm(const float* __restrict__ encoded, const float* __restrict__ Wih,
                                                  float* __restrict__ Gd){
  __shared__ float encL[512][16];
  int m0 = blockIdx.x * 64;
  int tid = threadIdx.x;
  for (int p = 0; p < 2; ++p){
    int k = p*256 + tid;
    for (int n = 0; n < 16; ++n) encL[k][n] = encoded[n*512 + k];
  }
  __syncthreads();
  int m_l = tid & 63, ng = tid >> 6;       // ng 0..3 -> n = ng*4+i
  float acc[4] = {0.f,0.f,0.f,0.f};
  const float* wrow = Wih + (size_t)(m0 + m_l)*512;
  for (int k = 0; k < 512; k += 4){
    float4 w4 = *(const float4*)&wrow[k];
#pragma unroll
    for (int i=0;i<4;++i){
      int n = ng*4 + i;
      acc[i] += w4.x*encL[k][n] + w4.y*encL[k+1][n] + w4.z*encL[k+2][n] + w4.w*encL[k+3][n];
    }
  }
#pragma unroll
  for (int i=0;i<4;++i) Gd[(size_t)(ng*4+i)*G4 + m0 + m_l] = acc[i];
}

__global__ __launch_bounds__(512) void k_h0c0(const float* __restrict__ Gd,
                                              const float* __restrict__ bih, const float* __restrict__ bhh,
                                              float* __restrict__ h0, float* __restrict__ c0){
  int b = blockIdx.x, u = threadIdx.x;
  float gi_ = Gd[(size_t)b*G4 + u]        + bih[u]      + bhh[u];
  float gg  = Gd[(size_t)b*G4 + u + 1024] + bih[u+1024] + bhh[u+1024];
  float go  = Gd[(size_t)b*G4 + u + 1536] + bih[u+1536] + bhh[u+1536];
  float cv = fsig(gi_)*ftanhf(gg);
  float hv = fsig(go)*ftanhf(cv);
  h0[b*RNN+u] = hv; c0[b*RNN+u] = cv;
}

// ---------- hoisted gate halves ----------
__global__ __launch_bounds__(256) void k_pre_gemm(const float* __restrict__ h0,
                                                  const float* __restrict__ Wih, const float* __restrict__ Whh,
                                                  const float* __restrict__ bih, const float* __restrict__ bhh,
                                                  float* __restrict__ g1h, float* __restrict__ g2x){
  __shared__ float hL[512][16];
  int m0 = blockIdx.x * 64;
  int tid = threadIdx.x;
  for (int p = 0; p < 2; ++p){
    int k = p*256 + tid;
    for (int n = 0; n < 16; ++n) hL[k][n] = h0[n*512 + k];
  }
  __syncthreads();
  int m_l = tid & 63, ng = tid >> 6;
  int m = m0 + m_l;
  float a1[4] = {0.f,0.f,0.f,0.f}, a2[4] = {0.f,0.f,0.f,0.f};
  const float* w1 = Whh + (size_t)m*512;
  const float* w2 = Wih + (size_t)m*512;
  for (int k = 0; k < 512; k += 4){
    float4 v1 = *(const float4*)&w1[k];
    float4 v2 = *(const float4*)&w2[k];
#pragma unroll
    for (int i=0;i<4;++i){
      int n = ng*4 + i;
      float x0 = hL[k][n], x1 = hL[k+1][n], x2 = hL[k+2][n], x3 = hL[k+3][n];
      a1[i] += v1.x*x0 + v1.y*x1 + v1.z*x2 + v1.w*x3;
      a2[i] += v2.x*x0 + v2.y*x1 + v2.z*x2 + v2.w*x3;
    }
  }
  float bb = bih[m] + bhh[m];
#pragma unroll
  for (int i=0;i<4;++i){
    g1h[(size_t)(ng*4+i)*G4 + m] = a1[i] + bb;
    g2x[(size_t)(ng*4+i)*G4 + m] = a2[i] + bb;
  }
}

// ---------- batched GEMM: G[480][M] = (W[Mx512] @ X[512x480])^T ----------
template<int MODE>
__global__ __launch_bounds__(256) void k_gemm_nt(const float* __restrict__ W,
                                                 const float* __restrict__ Xsrc,
                                                 const int* __restrict__ gt,
                                                 const float* __restrict__ embw,
                                                 float* __restrict__ G, int M){
  __shared__ float As[64][36];
  __shared__ float Bs[32][64];
  int m0 = blockIdx.x * 64, n0 = blockIdx.y * 64;
  int tid = threadIdx.x;
  int tm = tid >> 4, tn = tid & 15;
  float acc[4][4];
#pragma unroll
  for (int i=0;i<4;++i)
#pragma unroll
    for (int j=0;j<4;++j) acc[i][j] = 0.f;

  int sArow = tid >> 2, sAk = (tid & 3)*8;
  const float* arow = W + (size_t)(m0 + sArow)*512 + sAk;
  int n_l = tid & 63, kg = tid >> 6;
  int btc = n0 + n_l; if (btc > 479) btc = 479;
  const float* bcol;
  if (MODE == 0) bcol = embw + (size_t)gt[btc]*512 + kg*8;
  else           bcol = Xsrc + (size_t)btc*512 + kg*8;

  for (int ks = 0; ks < 16; ++ks){
    int k0 = ks*32;
    __syncthreads();
    *(float4*)&As[sArow][sAk]   = *(const float4*)(arow + k0);
    *(float4*)&As[sArow][sAk+4] = *(const float4*)(arow + k0 + 4);
    float4 b0 = *(const float4*)(bcol + k0);
    float4 b1 = *(const float4*)(bcol + k0 + 4);
    Bs[kg*8+0][n_l] = b0.x; Bs[kg*8+1][n_l] = b0.y; Bs[kg*8+2][n_l] = b0.z; Bs[kg*8+3][n_l] = b0.w;
    Bs[kg*8+4][n_l] = b1.x; Bs[kg*8+5][n_l] = b1.y; Bs[kg*8+6][n_l] = b1.z; Bs[kg*8+7][n_l] = b1.w;
    __syncthreads();
#pragma unroll 8
    for (int k = 0; k < 32; ++k){
      float4 bv = *(const float4*)&Bs[k][tn*4];
      float av0 = As[tm*4+0][k], av1 = As[tm*4+1][k], av2 = As[tm*4+2][k], av3 = As[tm*4+3][k];
      acc[0][0] += av0*bv.x; acc[0][1] += av0*bv.y; acc[0][2] += av0*bv.z; acc[0][3] += av0*bv.w;
      acc[1][0] += av1*bv.x; acc[1][1] += av1*bv.y; acc[1][2] += av1*bv.z; acc[1][3] += av1*bv.w;
      acc[2][0] += av2*bv.x; acc[2][1] += av2*bv.y; acc[2][2] += av2*bv.z; acc[2][3] += av2*bv.w;
      acc[3][0] += av3*bv.x; acc[3][1] += av3*bv.y; acc[3][2] += av3*bv.z; acc[3][3] += av3*bv.w;
    }
  }
#pragma unroll
  for (int ni=0; ni<4; ++ni){
    int n = n0 + tn*4 + ni;
    if (n < 480){
#pragma unroll
      for (int mi=0; mi<4; ++mi)
        G[(size_t)n*M + m0 + tm*4 + mi] = acc[mi][ni];
    }
  }
}

// ---------- LSTM pointwise ----------
__global__ __launch_bounds__(512) void k_lstm1(const float* __restrict__ G1, const float* __restrict__ g1h,
                                               const float* __restrict__ c0,
                                               float* __restrict__ h1, float* __restrict__ c1){
  int bt = blockIdx.x, b = bt / TMAX, u = threadIdx.x;
  float gi_ = G1[(size_t)bt*G4 + u]        + g1h[(size_t)b*G4 + u];
  float gf  = G1[(size_t)bt*G4 + u + 512]  + g1h[(size_t)b*G4 + u + 512];
  float gg  = G1[(size_t)bt*G4 + u + 1024] + g1h[(size_t)b*G4 + u + 1024];
  float go  = G1[(size_t)bt*G4 + u + 1536] + g1h[(size_t)b*G4 + u + 1536];
  float cv = fsig(gf)*c0[b*RNN+u] + fsig(gi_)*ftanhf(gg);
  float hv = fsig(go)*ftanhf(cv);
  h1[(size_t)bt*RNN + u] = hv; c1[(size_t)bt*RNN + u] = cv;
}
__global__ __launch_bounds__(512) void k_lstm2(const float* __restrict__ G2, const float* __restrict__ g2x,
                                               const float* __restrict__ c1, float* __restrict__ h2){
  int bt = blockIdx.x, b = bt / TMAX, u = threadIdx.x;
  float gi_ = G2[(size_t)bt*G4 + u]        + g2x[(size_t)b*G4 + u];
  float gf  = G2[(size_t)bt*G4 + u + 512]  + g2x[(size_t)b*G4 + u + 512];
  float gg  = G2[(size_t)bt*G4 + u + 1024] + g2x[(size_t)b*G4 + u + 1024];
  float go  = G2[(size_t)bt*G4 + u + 1536] + g2x[(size_t)b*G4 + u + 1536];
  float cv = fsig(gf)*c1[(size_t)bt*RNN+u] + fsig(gi_)*ftanhf(gg);
  float hv = fsig(go)*ftanhf(cv);
  h2[(size_t)bt*RNN + u] = hv;
}

// ---------- scores ----------
__global__ __launch_bounds__(512) void k_sc(const float* __restrict__ fp, const float* __restrict__ sp,
                                            const float* __restrict__ apw, float* __restrict__ sc){
  __shared__ float spL[TMAX][516];
  __shared__ float apwL[512];
  int b = blockIdx.x, hw0 = blockIdx.y * 32;
  int tid = threadIdx.x, lane = tid & 63, wave = tid >> 6;
  for (int t = 0; t < TMAX; ++t) spL[t][tid] = sp[((size_t)(b*TMAX + t))*ATTN + tid];
  if (tid < 512) apwL[tid] = apw[tid];
  __syncthreads();
#pragma unroll
  for (int r = 0; r < 4; ++r){
    int row = hw0 + wave*4 + r;
    const float* frow = fp + ((size_t)b*HWD + row)*ATTN;
    float acc[TMAX];
#pragma unroll
    for (int t=0;t<TMAX;++t) acc[t] = 0.f;
#pragma unroll
    for (int a0 = 0; a0 < 8; ++a0){
      int a = a0*64 + lane;
      float f = frow[a];
      float w = apwL[a];
#pragma unroll
      for (int t=0;t<TMAX;++t) acc[t] += w * ftanhf(f + spL[t][a]);
    }
#pragma unroll
    for (int t=0;t<TMAX;++t){
      float s = acc[t];
#pragma unroll
      for (int off = 32; off; off >>= 1) s += __shfl_xor(s, off);
      if (lane == 0) sc[((size_t)(b*TMAX + t))*HWD + row] = s;
    }
  }
}

// ---------- softmax ----------
__global__ __launch_bounds__(256) void k_smax(const float* __restrict__ sc, float* __restrict__ attn){
  __shared__ float red[256];
  int bt = blockIdx.x, tid = threadIdx.x;
  float v0 = sc[(size_t)bt*HWD + tid], v1 = sc[(size_t)bt*HWD + tid + 256];
  red[tid] = fmaxf(v0, v1); __syncthreads();
  for (int sd=128; sd; sd>>=1){ if (tid < sd) red[tid] = fmaxf(red[tid], red[tid+sd]); __syncthreads(); }
  float mx = red[0]; __syncthreads();
  float e0 = __expf(v0-mx), e1 = __expf(v1-mx);
  red[tid] = e0+e1; __syncthreads();
  for (int sd=128; sd; sd>>=1){ if (tid < sd) red[tid] += red[tid+sd]; __syncthreads(); }
  float inv = 1.0f / red[0];
  attn[(size_t)bt*HWD + tid]     = e0*inv;
  attn[(size_t)bt*HWD + tid+256] = e1*inv;
}

// ---------- glimpse partials over hw-chunks of 128 ----------
__global__ __launch_bounds__(512) void k_glimpse(const float* __restrict__ attn, const float* __restrict__ feats,
                                                 float* __restrict__ gpart){
  __shared__ float atL[128][32];
  int b = blockIdx.x, hc = blockIdx.y;
  int hw0 = hc*128;
  int tid = threadIdx.x;
  int flat = tid;
#pragma unroll
  for (int rep = 0; rep < 8; ++rep){
    int hw_l = flat >> 5, t = flat & 31;
    atL[hw_l][t] = (t < TMAX) ? attn[((size_t)(b*TMAX + t))*HWD + hw0 + hw_l] : 0.f;
    flat += 512;
  }
  __syncthreads();
  const float* fb = feats + ((size_t)(b*FEAT + tid))*HWD + hw0;   // thread = channel c
  float acc[32];
#pragma unroll
  for (int t=0;t<32;++t) acc[t] = 0.f;
  for (int hq = 0; hq < 32; ++hq){
    float4 f4 = *(const float4*)(fb + hq*4);
#pragma unroll
    for (int j = 0; j < 4; ++j){
      float f = (j==0)?f4.x:(j==1)?f4.y:(j==2)?f4.z:f4.w;
#pragma unroll
      for (int t4 = 0; t4 < 8; ++t4){
        float4 a4 = *(const float4*)&atL[hq*4+j][t4*4];
        acc[t4*4+0] += a4.x*f; acc[t4*4+1] += a4.y*f; acc[t4*4+2] += a4.z*f; acc[t4*4+3] += a4.w*f;
      }
    }
  }
#pragma unroll
  for (int t = 0; t < TMAX; ++t)
    gpart[(((size_t)hc*BB + b)*TMAX + t)*FEAT + tid] = acc[t];
}

// ---------- logits ----------
__global__ __launch_bounds__(512) void k_logits(const float* __restrict__ gpart,
                                                const float* __restrict__ outw, const float* __restrict__ outb,
                                                float* __restrict__ out){
  __shared__ float gl[512];
  __shared__ float part[4][128];
  int bt = blockIdx.x, b = bt / TMAX, t = bt % TMAX;
  int tid = threadIdx.x;
  float g = 0.f;
#pragma unroll
  for (int p = 0; p < 4; ++p)
    g += gpart[(((size_t)p*BB + b)*TMAX + t)*FEAT + tid];
  gl[tid] = g;
  __syncthreads();
  int vg = tid >> 7, v = tid & 127;
  int vv = v < VOCABP1 ? v : VOCABP1-1;
  const float* wr = outw + (size_t)vv*512 + vg*128;
  float s = 0.f;
  for (int k = 0; k < 128; k += 4){
    float4 w4 = *(const float4*)&wr[k];
    s += w4.x*gl[vg*128+k] + w4.y*gl[vg*128+k+1] + w4.z*gl[vg*128+k+2] + w4.w*gl[vg*128+k+3];
  }
  part[vg][v] = s;
  __syncthreads();
  if (tid < VOCABP1)
    out[(size_t)bt*VOCABP1 + tid] = part[0][tid] + part[1][tid] + part[2][tid] + part[3][tid] + outb[tid];
}

extern "C" void kernel_launch(void* const* d_in, const int* in_sizes, int n_in,
                              void* d_out, int out_size, void* d_ws, size_t ws_size,
                              hipStream_t stream){
  (void)in_sizes; (void)n_in; (void)out_size; (void)ws_size;
  const float* features = (const float*)d_in[0];
  const float* encoded  = (const float*)d_in[1];
  const float* embed_w  = (const float*)d_in[2];
  const float* dec_Wih  = (const float*)d_in[3];
  const float* dec_bih  = (const float*)d_in[5];
  const float* dec_bhh  = (const float*)d_in[6];
  const float* att_Wih  = (const float*)d_in[7];
  const float* att_Whh  = (const float*)d_in[8];
  const float* att_bih  = (const float*)d_in[9];
  const float* att_bhh  = (const float*)d_in[10];
  const float* fconv_w  = (const float*)d_in[11];
  const float* fconv_b  = (const float*)d_in[12];
  const float* scw      = (const float*)d_in[13];
  const float* apw      = (const float*)d_in[14];
  const float* outw     = (const float*)d_in[15];
  const float* outb     = (const float*)d_in[16];
  const int* gt         = (const int*)d_in[17];

  char* ws = (char*)d_ws;
  u16*  featsP = (u16*)(ws + 0);            // 10,813,440
  u16*  wB     = (u16*)(ws + 10813440);     //  4,718,592
  float* fp    = (float*)(ws + 15532032);   // 16,777,216
  float* Gd    = (float*)(ws + 32309248);   //    131,072
  float* h0    = (float*)(ws + 32440320);   //     32,768
  float* c0    = (float*)(ws + 32473088);   //     32,768
  float* g1h   = (float*)(ws + 32505856);   //    131,072
  float* g2x   = (float*)(ws + 32636928);   //    131,072
  float* G1    = (float*)(ws + 32768000);   //  3,932,160  (reused for G2)
  float* h1    = (float*)(ws + 36700160);   //    983,040
  float* c1    = (float*)(ws + 37683200);   //    983,040
  float* h2    = (float*)(ws + 38666240);   //    983,040
  float* sp    = (float*)(ws + 39649280);   //    983,040
  float* sc    = (float*)(ws + 40632320);   //    983,040
  float* attn  = (float*)(ws + 41615360);   //    983,040
  float* gpart = (float*)(ws + 42598400);   //  3,932,160 -> total 46,530,560 B

  hipMemsetAsync(featsP, 0, 10813440, stream);
  k_tfeat<<<dim3(8,8,16), 256, 0, stream>>>(features, featsP);
  k_twt<<<dim3(9216), 256, 0, stream>>>(fconv_w, wB);
  k_conv<<<dim3(64,8), 256, 0, stream>>>(featsP, wB, fconv_b, fp);

  k_dec_gemm<<<dim3(32), 256, 0, stream>>>(encoded, dec_Wih, Gd);
  k_h0c0<<<dim3(16), 512, 0, stream>>>(Gd, dec_bih, dec_bhh, h0, c0);
  k_pre_gemm<<<dim3(32), 256, 0, stream>>>(h0, att_Wih, att_Whh, att_bih, att_bhh, g1h, g2x);

  k_gemm_nt<0><<<dim3(32,8), 256, 0, stream>>>(att_Wih, nullptr, gt, embed_w, G1, G4);
  k_lstm1<<<dim3(480), 512, 0, stream>>>(G1, g1h, c0, h1, c1);
  k_gemm_nt<1><<<dim3(32,8), 256, 0, stream>>>(att_Whh, h1, nullptr, nullptr, G1, G4);
  k_lstm2<<<dim3(480), 512, 0, stream>>>(G1, g2x, c1, h2);
  k_gemm_nt<1><<<dim3(8,8), 256, 0, stream>>>(scw, h2, nullptr, nullptr, sp, ATTN);

  k_sc<<<dim3(16,16), 512, 0, stream>>>(fp, sp, apw, sc);
  k_smax<<<dim3(480), 256, 0, stream>>>(sc, attn);
  k_glimpse<<<dim3(16,4), 512, 0, stream>>>(attn, features, gpart);
  k_logits<<<dim3(480), 512, 0, stream>>>(gpart, outw, outb, (float*)d_out);
}

// Round 7
// 472.760 us; speedup vs baseline: 3.2463x; 1.1161x over previous
//
#include <hip/hip_runtime.h>
#include <hip/hip_bf16.h>
#include <stdint.h>

#define BB 16
#define TMAX 30
#define FEAT 512
#define RNN 512
#define ATTN 512
#define VOCABP1 111
#define HWD 512
#define PH 10
#define PW 66
#define PROWS 660
#define G4 2048
#define NHC 8   // glimpse hw chunks

typedef unsigned short u16;
typedef __attribute__((ext_vector_type(8))) unsigned short us8v;
typedef __attribute__((ext_vector_type(8))) short short8;
typedef __attribute__((ext_vector_type(4))) float f32x4;

__device__ __forceinline__ u16 f2b(float x){   // RNE
  unsigned int u = __builtin_bit_cast(unsigned int, x);
  unsigned int r = u + 0x7FFFu + ((u >> 16) & 1u);
  return (u16)(r >> 16);
}
__device__ __forceinline__ float fsig(float x){ return __fdividef(1.0f, 1.0f + __expf(-x)); }
__device__ __forceinline__ float ftanhf(float x){ return 1.0f - __fdividef(2.0f, __expf(2.0f*x) + 1.0f); }

// ---------- features [B,C,HW] fp32 -> padded bf16 [B, PROWS, C] ----------
__global__ __launch_bounds__(256) void k_tfeat(const float* __restrict__ feats, u16* __restrict__ featsP){
  __shared__ float tile[64*65];
  int b = blockIdx.z, c0 = blockIdx.y*64, hw0 = blockIdx.x*64;
  int tid = threadIdx.x;
  int tx = tid & 63, ty = tid >> 6;
#pragma unroll
  for (int r = 0; r < 16; ++r){
    int cl = ty*16 + r;
    tile[cl*65 + tx] = feats[((size_t)(b*FEAT + c0 + cl))*HWD + hw0 + tx];
  }
  __syncthreads();
#pragma unroll
  for (int r = 0; r < 16; ++r){
    int hwl = ty*16 + r;
    int hw = hw0 + hwl;
    int rowP = hw + 2*(hw >> 6) + 67;   // (y+1)*66 + (x+1)
    featsP[((size_t)b*PROWS + rowP)*FEAT + c0 + tx] = f2b(tile[tx*65 + hwl]);
  }
}

// ---------- conv weights [O,C,3,3] fp32 -> bf16 wB[k9][o][c] ----------
__global__ __launch_bounds__(256) void k_twt(const float* __restrict__ w, u16* __restrict__ wB){
  int idx = blockIdx.x*256 + threadIdx.x;
  if (idx >= 9*512*512) return;
  int c = idx & 511; int n = (idx >> 9) & 511; int k9 = idx >> 18;
  wB[idx] = f2b(w[((size_t)(n*512 + c))*9 + k9]);
}

// ---------- conv as implicit-im2col MFMA bf16 GEMM (register staging) ----------
__global__ __launch_bounds__(256) void k_conv(const u16* __restrict__ featsP, const u16* __restrict__ wB,
                                              const float* __restrict__ bias, float* __restrict__ fp){
  __shared__ __align__(16) u16 As[128*32];
  __shared__ __align__(16) u16 Bs[64*32];
  int m0 = blockIdx.x * 128, n0 = blockIdx.y * 64;
  int tid = threadIdx.x, lane = tid & 63, wave = tid >> 6;
  int wm = wave >> 1, wn = wave & 1;

  int kk = (lane & 3) * 8;
  int rA0 = 32*wave + (lane >> 2);
  int rA1 = rA0 + 16;
  int mA0 = m0 + rA0, mA1 = m0 + rA1;
  long baseA0 = ((long)((mA0 >> 9)*PH + ((mA0 >> 6) & 7) + 1)*PW + (mA0 & 63) + 1)*FEAT + kk;
  long baseA1 = ((long)((mA1 >> 9)*PH + ((mA1 >> 6) & 7) + 1)*PW + (mA1 & 63) + 1)*FEAT + kk;
  int nloc = 16*wave + (lane >> 2);
  long baseB = (long)(n0 + nloc)*512 + kk;

  f32x4 acc[4][2];
#pragma unroll
  for (int i=0;i<4;++i)
#pragma unroll
    for (int j=0;j<2;++j) acc[i][j] = (f32x4){0.f,0.f,0.f,0.f};

  int arow = wm*64 + (lane & 15);
  int akc  = (lane >> 4) * 8;
  int brow = wn*32 + (lane & 15);

  us8v a0c, a1c, bc;
  {
    long dA = (long)(-1*PW - 1)*FEAT;   // ks=0: o=0 -> dy=-1,dx=-1,c0=0
    a0c = *(const us8v*)(featsP + baseA0 + dA);
    a1c = *(const us8v*)(featsP + baseA1 + dA);
    bc  = *(const us8v*)(wB + baseB);
  }

  for (int ks = 0; ks < 144; ++ks){
    __syncthreads();
    *(us8v*)&As[rA0*32 + kk] = a0c;
    *(us8v*)&As[rA1*32 + kk] = a1c;
    *(us8v*)&Bs[nloc*32 + kk] = bc;
    __syncthreads();
    if (ks < 143){
      int kn = ks + 1;
      int o = kn >> 4;
      int c0 = (kn & 15) << 5;
      int dy = o/3 - 1, dx = o - (o/3)*3 - 1;
      long dA = (long)(dy*PW + dx)*FEAT + c0;
      long dB = (long)o*(512*512) + c0;
      a0c = *(const us8v*)(featsP + baseA0 + dA);
      a1c = *(const us8v*)(featsP + baseA1 + dA);
      bc  = *(const us8v*)(wB + baseB + dB);
    }
    short8 a[4], bfr[2];
#pragma unroll
    for (int mt=0; mt<4; ++mt) a[mt] = *(const short8*)&As[(arow + mt*16)*32 + akc];
#pragma unroll
    for (int nt=0; nt<2; ++nt) bfr[nt] = *(const short8*)&Bs[(brow + nt*16)*32 + akc];
#pragma unroll
    for (int mt=0; mt<4; ++mt)
#pragma unroll
      for (int nt=0; nt<2; ++nt)
        acc[mt][nt] = __builtin_amdgcn_mfma_f32_16x16x32_bf16(a[mt], bfr[nt], acc[mt][nt], 0, 0, 0);
  }
  int col = lane & 15;
  int rbase = (lane >> 4) * 4;
#pragma unroll
  for (int mt=0; mt<4; ++mt){
#pragma unroll
    for (int nt=0; nt<2; ++nt){
      int gn = n0 + wn*32 + nt*16 + col;
      float bv = bias[gn];
#pragma unroll
      for (int r=0; r<4; ++r){
        int gm = m0 + wm*64 + mt*16 + rbase + r;
        fp[(size_t)gm*ATTN + gn] = acc[mt][nt][r] + bv;
      }
    }
  }
}

// ---------- decoder gates GEMM: Gd[16][2048] ----------
__global__ __launch_bounds__(256) void k_dec_gemm(const float* __restrict__ encoded, const float* __restrict__ Wih,
                                                  float* __restrict__ Gd){
  __shared__ float encL[512][16];
  int m0 = blockIdx.x * 64;
  int tid = threadIdx.x;
  for (int p = 0; p < 2; ++p){
    int k = p*256 + tid;
    for (int n = 0; n < 16; ++n) encL[k][n] = encoded[n*512 + k];
  }
  __syncthreads();
  int m_l = tid & 63, ng = tid >> 6;
  float acc[4] = {0.f,0.f,0.f,0.f};
  const float* wrow = Wih + (size_t)(m0 + m_l)*512;
  for (int k = 0; k < 512; k += 4){
    float4 w4 = *(const float4*)&wrow[k];
#pragma unroll
    for (int i=0;i<4;++i){
      int n = ng*4 + i;
      acc[i] += w4.x*encL[k][n] + w4.y*encL[k+1][n] + w4.z*encL[k+2][n] + w4.w*encL[k+3][n];
    }
  }
#pragma unroll
  for (int i=0;i<4;++i) Gd[(size_t)(ng*4+i)*G4 + m0 + m_l] = acc[i];
}

__global__ __launch_bounds__(512) void k_h0c0(const float* __restrict__ Gd,
                                              const float* __restrict__ bih, const float* __restrict__ bhh,
                                              float* __restrict__ h0, float* __restrict__ c0){
  int b = blockIdx.x, u = threadIdx.x;
  float gi_ = Gd[(size_t)b*G4 + u]        + bih[u]      + bhh[u];
  float gg  = Gd[(size_t)b*G4 + u + 1024] + bih[u+1024] + bhh[u+1024];
  float go  = Gd[(size_t)b*G4 + u + 1536] + bih[u+1536] + bhh[u+1536];
  float cv = fsig(gi_)*ftanhf(gg);
  float hv = fsig(go)*ftanhf(cv);
  h0[b*RNN+u] = hv; c0[b*RNN+u] = cv;
}

// ---------- hoisted gate halves ----------
__global__ __launch_bounds__(256) void k_pre_gemm(const float* __restrict__ h0,
                                                  const float* __restrict__ Wih, const float* __restrict__ Whh,
                                                  const float* __restrict__ bih, const float* __restrict__ bhh,
                                                  float* __restrict__ g1h, float* __restrict__ g2x){
  __shared__ float hL[512][16];
  int m0 = blockIdx.x * 64;
  int tid = threadIdx.x;
  for (int p = 0; p < 2; ++p){
    int k = p*256 + tid;
    for (int n = 0; n < 16; ++n) hL[k][n] = h0[n*512 + k];
  }
  __syncthreads();
  int m_l = tid & 63, ng = tid >> 6;
  int m = m0 + m_l;
  float a1[4] = {0.f,0.f,0.f,0.f}, a2[4] = {0.f,0.f,0.f,0.f};
  const float* w1 = Whh + (size_t)m*512;
  const float* w2 = Wih + (size_t)m*512;
  for (int k = 0; k < 512; k += 4){
    float4 v1 = *(const float4*)&w1[k];
    float4 v2 = *(const float4*)&w2[k];
#pragma unroll
    for (int i=0;i<4;++i){
      int n = ng*4 + i;
      float x0 = hL[k][n], x1 = hL[k+1][n], x2 = hL[k+2][n], x3 = hL[k+3][n];
      a1[i] += v1.x*x0 + v1.y*x1 + v1.z*x2 + v1.w*x3;
      a2[i] += v2.x*x0 + v2.y*x1 + v2.z*x2 + v2.w*x3;
    }
  }
  float bb = bih[m] + bhh[m];
#pragma unroll
  for (int i=0;i<4;++i){
    g1h[(size_t)(ng*4+i)*G4 + m] = a1[i] + bb;
    g2x[(size_t)(ng*4+i)*G4 + m] = a2[i] + bb;
  }
}

// ---------- batched GEMM: G[480][M] = (W[Mx512] @ X[512x480])^T ----------
template<int MODE>
__global__ __launch_bounds__(256) void k_gemm_nt(const float* __restrict__ W,
                                                 const float* __restrict__ Xsrc,
                                                 const int* __restrict__ gt,
                                                 const float* __restrict__ embw,
                                                 float* __restrict__ G, int M){
  __shared__ float As[64][36];
  __shared__ float Bs[32][64];
  int m0 = blockIdx.x * 64, n0 = blockIdx.y * 64;
  int tid = threadIdx.x;
  int tm = tid >> 4, tn = tid & 15;
  float acc[4][4];
#pragma unroll
  for (int i=0;i<4;++i)
#pragma unroll
    for (int j=0;j<4;++j) acc[i][j] = 0.f;

  int sArow = tid >> 2, sAk = (tid & 3)*8;
  const float* arow = W + (size_t)(m0 + sArow)*512 + sAk;
  int n_l = tid & 63, kg = tid >> 6;
  int btc = n0 + n_l; if (btc > 479) btc = 479;
  const float* bcol;
  if (MODE == 0) bcol = embw + (size_t)gt[btc]*512 + kg*8;
  else           bcol = Xsrc + (size_t)btc*512 + kg*8;

  for (int ks = 0; ks < 16; ++ks){
    int k0 = ks*32;
    __syncthreads();
    *(float4*)&As[sArow][sAk]   = *(const float4*)(arow + k0);
    *(float4*)&As[sArow][sAk+4] = *(const float4*)(arow + k0 + 4);
    float4 b0 = *(const float4*)(bcol + k0);
    float4 b1 = *(const float4*)(bcol + k0 + 4);
    Bs[kg*8+0][n_l] = b0.x; Bs[kg*8+1][n_l] = b0.y; Bs[kg*8+2][n_l] = b0.z; Bs[kg*8+3][n_l] = b0.w;
    Bs[kg*8+4][n_l] = b1.x; Bs[kg*8+5][n_l] = b1.y; Bs[kg*8+6][n_l] = b1.z; Bs[kg*8+7][n_l] = b1.w;
    __syncthreads();
#pragma unroll 8
    for (int k = 0; k < 32; ++k){
      float4 bv = *(const float4*)&Bs[k][tn*4];
      float av0 = As[tm*4+0][k], av1 = As[tm*4+1][k], av2 = As[tm*4+2][k], av3 = As[tm*4+3][k];
      acc[0][0] += av0*bv.x; acc[0][1] += av0*bv.y; acc[0][2] += av0*bv.z; acc[0][3] += av0*bv.w;
      acc[1][0] += av1*bv.x; acc[1][1] += av1*bv.y; acc[1][2] += av1*bv.z; acc[1][3] += av1*bv.w;
      acc[2][0] += av2*bv.x; acc[2][1] += av2*bv.y; acc[2][2] += av2*bv.z; acc[2][3] += av2*bv.w;
      acc[3][0] += av3*bv.x; acc[3][1] += av3*bv.y; acc[3][2] += av3*bv.z; acc[3][3] += av3*bv.w;
    }
  }
#pragma unroll
  for (int ni=0; ni<4; ++ni){
    int n = n0 + tn*4 + ni;
    if (n < 480){
#pragma unroll
      for (int mi=0; mi<4; ++mi)
        G[(size_t)n*M + m0 + tm*4 + mi] = acc[mi][ni];
    }
  }
}

// ---------- LSTM pointwise ----------
__global__ __launch_bounds__(512) void k_lstm1(const float* __restrict__ G1, const float* __restrict__ g1h,
                                               const float* __restrict__ c0,
                                               float* __restrict__ h1, float* __restrict__ c1){
  int bt = blockIdx.x, b = bt / TMAX, u = threadIdx.x;
  float gi_ = G1[(size_t)bt*G4 + u]        + g1h[(size_t)b*G4 + u];
  float gf  = G1[(size_t)bt*G4 + u + 512]  + g1h[(size_t)b*G4 + u + 512];
  float gg  = G1[(size_t)bt*G4 + u + 1024] + g1h[(size_t)b*G4 + u + 1024];
  float go  = G1[(size_t)bt*G4 + u + 1536] + g1h[(size_t)b*G4 + u + 1536];
  float cv = fsig(gf)*c0[b*RNN+u] + fsig(gi_)*ftanhf(gg);
  float hv = fsig(go)*ftanhf(cv);
  h1[(size_t)bt*RNN + u] = hv; c1[(size_t)bt*RNN + u] = cv;
}
__global__ __launch_bounds__(512) void k_lstm2(const float* __restrict__ G2, const float* __restrict__ g2x,
                                               const float* __restrict__ c1, float* __restrict__ h2){
  int bt = blockIdx.x, b = bt / TMAX, u = threadIdx.x;
  float gi_ = G2[(size_t)bt*G4 + u]        + g2x[(size_t)b*G4 + u];
  float gf  = G2[(size_t)bt*G4 + u + 512]  + g2x[(size_t)b*G4 + u + 512];
  float gg  = G2[(size_t)bt*G4 + u + 1024] + g2x[(size_t)b*G4 + u + 1024];
  float go  = G2[(size_t)bt*G4 + u + 1536] + g2x[(size_t)b*G4 + u + 1536];
  float cv = fsig(gf)*c1[(size_t)bt*RNN+u] + fsig(gi_)*ftanhf(gg);
  float hv = fsig(go)*ftanhf(cv);
  h2[(size_t)bt*RNN + u] = hv;
}

// ---------- scores: t-chunked for occupancy ----------
__global__ __launch_bounds__(512) void k_sc(const float* __restrict__ fp, const float* __restrict__ sp,
                                            const float* __restrict__ apw, float* __restrict__ sc){
  __shared__ float spL[8][516];
  __shared__ float apwL[512];
  int b = blockIdx.x, hw0 = blockIdx.y * 32, t0 = blockIdx.z * 8;
  int tid = threadIdx.x, lane = tid & 63, wave = tid >> 6;
  for (int i = tid; i < 8*512; i += 512){
    int t = i >> 9, a = i & 511;
    int tg = t0 + t;
    spL[t][a] = (tg < TMAX) ? sp[((size_t)(b*TMAX + tg))*ATTN + a] : 0.f;
  }
  apwL[tid] = apw[tid & 511] * 0.f + apw[tid];   // tid<512 always
  __syncthreads();
#pragma unroll
  for (int r = 0; r < 4; ++r){
    int row = hw0 + wave*4 + r;
    const float* frow = fp + ((size_t)b*HWD + row)*ATTN;
    float acc[8];
#pragma unroll
    for (int t=0;t<8;++t) acc[t] = 0.f;
#pragma unroll
    for (int a0 = 0; a0 < 8; ++a0){
      int a = a0*64 + lane;
      float f = frow[a];
      float w = apwL[a];
#pragma unroll
      for (int t=0;t<8;++t) acc[t] += w * ftanhf(f + spL[t][a]);
    }
#pragma unroll
    for (int t=0;t<8;++t){
      float s = acc[t];
#pragma unroll
      for (int off = 32; off; off >>= 1) s += __shfl_xor(s, off);
      if (lane == 0 && (t0 + t) < TMAX) sc[((size_t)(b*TMAX + t0 + t))*HWD + row] = s;
    }
  }
}

// ---------- softmax ----------
__global__ __launch_bounds__(256) void k_smax(const float* __restrict__ sc, float* __restrict__ attn){
  __shared__ float red[256];
  int bt = blockIdx.x, tid = threadIdx.x;
  float v0 = sc[(size_t)bt*HWD + tid], v1 = sc[(size_t)bt*HWD + tid + 256];
  red[tid] = fmaxf(v0, v1); __syncthreads();
  for (int sd=128; sd; sd>>=1){ if (tid < sd) red[tid] = fmaxf(red[tid], red[tid+sd]); __syncthreads(); }
  float mx = red[0]; __syncthreads();
  float e0 = __expf(v0-mx), e1 = __expf(v1-mx);
  red[tid] = e0+e1; __syncthreads();
  for (int sd=128; sd; sd>>=1){ if (tid < sd) red[tid] += red[tid+sd]; __syncthreads(); }
  float inv = __fdividef(1.0f, red[0]);
  attn[(size_t)bt*HWD + tid]     = e0*inv;
  attn[(size_t)bt*HWD + tid+256] = e1*inv;
}

// ---------- glimpse partials over hw-chunks of 64 ----------
__global__ __launch_bounds__(512) void k_glimpse(const float* __restrict__ attn, const float* __restrict__ feats,
                                                 float* __restrict__ gpart){
  __shared__ float atL[64][32];
  int b = blockIdx.x, hc = blockIdx.y;
  int hw0 = hc*64;
  int tid = threadIdx.x;
  int flat = tid;
#pragma unroll
  for (int rep = 0; rep < 4; ++rep){
    int hw_l = flat >> 5, t = flat & 31;
    atL[hw_l][t] = (t < TMAX) ? attn[((size_t)(b*TMAX + t))*HWD + hw0 + hw_l] : 0.f;
    flat += 512;
  }
  __syncthreads();
  const float* fb = feats + ((size_t)(b*FEAT + tid))*HWD + hw0;   // thread = channel c
  float acc[32];
#pragma unroll
  for (int t=0;t<32;++t) acc[t] = 0.f;
  for (int hq = 0; hq < 16; ++hq){
    float4 f4 = *(const float4*)(fb + hq*4);
#pragma unroll
    for (int j = 0; j < 4; ++j){
      float f = (j==0)?f4.x:(j==1)?f4.y:(j==2)?f4.z:f4.w;
#pragma unroll
      for (int t4 = 0; t4 < 8; ++t4){
        float4 a4 = *(const float4*)&atL[hq*4+j][t4*4];
        acc[t4*4+0] += a4.x*f; acc[t4*4+1] += a4.y*f; acc[t4*4+2] += a4.z*f; acc[t4*4+3] += a4.w*f;
      }
    }
  }
#pragma unroll
  for (int t = 0; t < TMAX; ++t)
    gpart[(((size_t)hc*BB + b)*TMAX + t)*FEAT + tid] = acc[t];
}

// ---------- logits ----------
__global__ __launch_bounds__(512) void k_logits(const float* __restrict__ gpart,
                                                const float* __restrict__ outw, const float* __restrict__ outb,
                                                float* __restrict__ out){
  __shared__ float gl[512];
  __shared__ float part[4][128];
  int bt = blockIdx.x, b = bt / TMAX, t = bt % TMAX;
  int tid = threadIdx.x;
  float g = 0.f;
#pragma unroll
  for (int p = 0; p < NHC; ++p)
    g += gpart[(((size_t)p*BB + b)*TMAX + t)*FEAT + tid];
  gl[tid] = g;
  __syncthreads();
  int vg = tid >> 7, v = tid & 127;
  int vv = v < VOCABP1 ? v : VOCABP1-1;
  const float* wr = outw + (size_t)vv*512 + vg*128;
  float s = 0.f;
  for (int k = 0; k < 128; k += 4){
    float4 w4 = *(const float4*)&wr[k];
    s += w4.x*gl[vg*128+k] + w4.y*gl[vg*128+k+1] + w4.z*gl[vg*128+k+2] + w4.w*gl[vg*128+k+3];
  }
  part[vg][v] = s;
  __syncthreads();
  if (tid < VOCABP1)
    out[(size_t)bt*VOCABP1 + tid] = part[0][tid] + part[1][tid] + part[2][tid] + part[3][tid] + outb[tid];
}

extern "C" void kernel_launch(void* const* d_in, const int* in_sizes, int n_in,
                              void* d_out, int out_size, void* d_ws, size_t ws_size,
                              hipStream_t stream){
  (void)in_sizes; (void)n_in; (void)out_size; (void)ws_size;
  const float* features = (const float*)d_in[0];
  const float* encoded  = (const float*)d_in[1];
  const float* embed_w  = (const float*)d_in[2];
  const float* dec_Wih  = (const float*)d_in[3];
  const float* dec_bih  = (const float*)d_in[5];
  const float* dec_bhh  = (const float*)d_in[6];
  const float* att_Wih  = (const float*)d_in[7];
  const float* att_Whh  = (const float*)d_in[8];
  const float* att_bih  = (const float*)d_in[9];
  const float* att_bhh  = (const float*)d_in[10];
  const float* fconv_w  = (const float*)d_in[11];
  const float* fconv_b  = (const float*)d_in[12];
  const float* scw      = (const float*)d_in[13];
  const float* apw      = (const float*)d_in[14];
  const float* outw     = (const float*)d_in[15];
  const float* outb     = (const float*)d_in[16];
  const int* gt         = (const int*)d_in[17];

  char* ws = (char*)d_ws;
  u16*  featsP = (u16*)(ws + 0);            // 10,813,440
  u16*  wB     = (u16*)(ws + 10813440);     //  4,718,592
  float* fp    = (float*)(ws + 15532032);   // 16,777,216
  float* Gd    = (float*)(ws + 32309248);   //    131,072
  float* h0    = (float*)(ws + 32440320);   //     32,768
  float* c0    = (float*)(ws + 32473088);   //     32,768
  float* g1h   = (float*)(ws + 32505856);   //    131,072
  float* g2x   = (float*)(ws + 32636928);   //    131,072
  float* G1    = (float*)(ws + 32768000);   //  3,932,160  (reused for G2)
  float* h1    = (float*)(ws + 36700160);   //    983,040
  float* c1    = (float*)(ws + 37683200);   //    983,040
  float* h2    = (float*)(ws + 38666240);   //    983,040
  float* sp    = (float*)(ws + 39649280);   //    983,040
  float* sc    = (float*)(ws + 40632320);   //    983,040
  float* attn  = (float*)(ws + 41615360);   //    983,040
  float* gpart = (float*)(ws + 42598400);   //  7,864,320 -> total 50,462,720 B

  hipMemsetAsync(featsP, 0, 10813440, stream);
  k_tfeat<<<dim3(8,8,16), 256, 0, stream>>>(features, featsP);
  k_twt<<<dim3(9216), 256, 0, stream>>>(fconv_w, wB);
  k_conv<<<dim3(64,8), 256, 0, stream>>>(featsP, wB, fconv_b, fp);

  k_dec_gemm<<<dim3(32), 256, 0, stream>>>(encoded, dec_Wih, Gd);
  k_h0c0<<<dim3(16), 512, 0, stream>>>(Gd, dec_bih, dec_bhh, h0, c0);
  k_pre_gemm<<<dim3(32), 256, 0, stream>>>(h0, att_Wih, att_Whh, att_bih, att_bhh, g1h, g2x);

  k_gemm_nt<0><<<dim3(32,8), 256, 0, stream>>>(att_Wih, nullptr, gt, embed_w, G1, G4);
  k_lstm1<<<dim3(480), 512, 0, stream>>>(G1, g1h, c0, h1, c1);
  k_gemm_nt<1><<<dim3(32,8), 256, 0, stream>>>(att_Whh, h1, nullptr, nullptr, G1, G4);
  k_lstm2<<<dim3(480), 512, 0, stream>>>(G1, g2x, c1, h2);
  k_gemm_nt<1><<<dim3(8,8), 256, 0, stream>>>(scw, h2, nullptr, nullptr, sp, ATTN);

  k_sc<<<dim3(16,16,4), 512, 0, stream>>>(fp, sp, apw, sc);
  k_smax<<<dim3(480), 256, 0, stream>>>(sc, attn);
  k_glimpse<<<dim3(16,NHC), 512, 0, stream>>>(attn, features, gpart);
  k_logits<<<dim3(480), 512, 0, stream>>>(gpart, outw, outb, (float*)d_out);
}

// Round 8
// 427.627 us; speedup vs baseline: 3.5889x; 1.1055x over previous
//
#include <hip/hip_runtime.h>
#include <hip/hip_bf16.h>
#include <stdint.h>

#define BB 16
#define TMAX 30
#define FEAT 512
#define RNN 512
#define ATTN 512
#define VOCABP1 111
#define HWD 512
#define PH 10
#define PW 66
#define PROWS 660
#define G4 2048
#define NHC 16   // glimpse hw chunks

typedef unsigned short u16;
typedef __attribute__((ext_vector_type(8))) unsigned short us8v;
typedef __attribute__((ext_vector_type(8))) short short8;
typedef __attribute__((ext_vector_type(4))) float f32x4;

__device__ __forceinline__ float b2f(u16 b){
  unsigned int u = ((unsigned int)b) << 16;
  return __builtin_bit_cast(float, u);
}
__device__ __forceinline__ u16 f2b(float x){   // RNE
  unsigned int u = __builtin_bit_cast(unsigned int, x);
  unsigned int r = u + 0x7FFFu + ((u >> 16) & 1u);
  return (u16)(r >> 16);
}
__device__ __forceinline__ float fsig(float x){ return __fdividef(1.0f, 1.0f + __expf(-x)); }
__device__ __forceinline__ float ftanhf(float x){ return 1.0f - __fdividef(2.0f, __expf(2.0f*x) + 1.0f); }

// ---------- features [B,C,HW] fp32 -> padded bf16 [B, PROWS, C] ----------
__global__ __launch_bounds__(256) void k_tfeat(const float* __restrict__ feats, u16* __restrict__ featsP){
  __shared__ float tile[64*65];
  int b = blockIdx.z, c0 = blockIdx.y*64, hw0 = blockIdx.x*64;
  int tid = threadIdx.x;
  int tx = tid & 63, ty = tid >> 6;
#pragma unroll
  for (int r = 0; r < 16; ++r){
    int cl = ty*16 + r;
    tile[cl*65 + tx] = feats[((size_t)(b*FEAT + c0 + cl))*HWD + hw0 + tx];
  }
  __syncthreads();
#pragma unroll
  for (int r = 0; r < 16; ++r){
    int hwl = ty*16 + r;
    int hw = hw0 + hwl;
    int rowP = hw + 2*(hw >> 6) + 67;   // (y+1)*66 + (x+1)
    featsP[((size_t)b*PROWS + rowP)*FEAT + c0 + tx] = f2b(tile[tx*65 + hwl]);
  }
}

// ---------- conv weights [O,C,3,3] fp32 -> bf16 wB[k9][o][c] ----------
__global__ __launch_bounds__(256) void k_twt(const float* __restrict__ w, u16* __restrict__ wB){
  int idx = blockIdx.x*256 + threadIdx.x;
  if (idx >= 9*512*512) return;
  int c = idx & 511; int n = (idx >> 9) & 511; int k9 = idx >> 18;
  wB[idx] = f2b(w[((size_t)(n*512 + c))*9 + k9]);
}

// ---------- conv as implicit-im2col MFMA bf16 GEMM; epilogue stores e^{2v} ----------
__global__ __launch_bounds__(256) void k_conv(const u16* __restrict__ featsP, const u16* __restrict__ wB,
                                              const float* __restrict__ bias, float* __restrict__ fpe){
  __shared__ __align__(16) u16 As[128*32];
  __shared__ __align__(16) u16 Bs[64*32];
  int m0 = blockIdx.x * 128, n0 = blockIdx.y * 64;
  int tid = threadIdx.x, lane = tid & 63, wave = tid >> 6;
  int wm = wave >> 1, wn = wave & 1;

  int kk = (lane & 3) * 8;
  int rA0 = 32*wave + (lane >> 2);
  int rA1 = rA0 + 16;
  int mA0 = m0 + rA0, mA1 = m0 + rA1;
  long baseA0 = ((long)((mA0 >> 9)*PH + ((mA0 >> 6) & 7) + 1)*PW + (mA0 & 63) + 1)*FEAT + kk;
  long baseA1 = ((long)((mA1 >> 9)*PH + ((mA1 >> 6) & 7) + 1)*PW + (mA1 & 63) + 1)*FEAT + kk;
  int nloc = 16*wave + (lane >> 2);
  long baseB = (long)(n0 + nloc)*512 + kk;

  f32x4 acc[4][2];
#pragma unroll
  for (int i=0;i<4;++i)
#pragma unroll
    for (int j=0;j<2;++j) acc[i][j] = (f32x4){0.f,0.f,0.f,0.f};

  int arow = wm*64 + (lane & 15);
  int akc  = (lane >> 4) * 8;
  int brow = wn*32 + (lane & 15);

  us8v a0c, a1c, bc;
  {
    long dA = (long)(-1*PW - 1)*FEAT;   // ks=0: o=0 -> dy=-1,dx=-1,c0=0
    a0c = *(const us8v*)(featsP + baseA0 + dA);
    a1c = *(const us8v*)(featsP + baseA1 + dA);
    bc  = *(const us8v*)(wB + baseB);
  }

  for (int ks = 0; ks < 144; ++ks){
    __syncthreads();
    *(us8v*)&As[rA0*32 + kk] = a0c;
    *(us8v*)&As[rA1*32 + kk] = a1c;
    *(us8v*)&Bs[nloc*32 + kk] = bc;
    __syncthreads();
    if (ks < 143){
      int kn = ks + 1;
      int o = kn >> 4;
      int c0 = (kn & 15) << 5;
      int dy = o/3 - 1, dx = o - (o/3)*3 - 1;
      long dA = (long)(dy*PW + dx)*FEAT + c0;
      long dB = (long)o*(512*512) + c0;
      a0c = *(const us8v*)(featsP + baseA0 + dA);
      a1c = *(const us8v*)(featsP + baseA1 + dA);
      bc  = *(const us8v*)(wB + baseB + dB);
    }
    short8 a[4], bfr[2];
#pragma unroll
    for (int mt=0; mt<4; ++mt) a[mt] = *(const short8*)&As[(arow + mt*16)*32 + akc];
#pragma unroll
    for (int nt=0; nt<2; ++nt) bfr[nt] = *(const short8*)&Bs[(brow + nt*16)*32 + akc];
#pragma unroll
    for (int mt=0; mt<4; ++mt)
#pragma unroll
      for (int nt=0; nt<2; ++nt)
        acc[mt][nt] = __builtin_amdgcn_mfma_f32_16x16x32_bf16(a[mt], bfr[nt], acc[mt][nt], 0, 0, 0);
  }
  int col = lane & 15;
  int rbase = (lane >> 4) * 4;
#pragma unroll
  for (int mt=0; mt<4; ++mt){
#pragma unroll
    for (int nt=0; nt<2; ++nt){
      int gn = n0 + wn*32 + nt*16 + col;
      float bv = bias[gn];
#pragma unroll
      for (int r=0; r<4; ++r){
        int gm = m0 + wm*64 + mt*16 + rbase + r;
        fpe[(size_t)gm*ATTN + gn] = __expf(2.0f*(acc[mt][nt][r] + bv));
      }
    }
  }
}

// ---------- decoder gates GEMM: Gd[16][2048] ----------
__global__ __launch_bounds__(256) void k_dec_gemm(const float* __restrict__ encoded, const float* __restrict__ Wih,
                                                  float* __restrict__ Gd){
  __shared__ float encL[512][16];
  int m0 = blockIdx.x * 64;
  int tid = threadIdx.x;
  for (int p = 0; p < 2; ++p){
    int k = p*256 + tid;
    for (int n = 0; n < 16; ++n) encL[k][n] = encoded[n*512 + k];
  }
  __syncthreads();
  int m_l = tid & 63, ng = tid >> 6;
  float acc[4] = {0.f,0.f,0.f,0.f};
  const float* wrow = Wih + (size_t)(m0 + m_l)*512;
  for (int k = 0; k < 512; k += 4){
    float4 w4 = *(const float4*)&wrow[k];
#pragma unroll
    for (int i=0;i<4;++i){
      int n = ng*4 + i;
      acc[i] += w4.x*encL[k][n] + w4.y*encL[k+1][n] + w4.z*encL[k+2][n] + w4.w*encL[k+3][n];
    }
  }
#pragma unroll
  for (int i=0;i<4;++i) Gd[(size_t)(ng*4+i)*G4 + m0 + m_l] = acc[i];
}

__global__ __launch_bounds__(512) void k_h0c0(const float* __restrict__ Gd,
                                              const float* __restrict__ bih, const float* __restrict__ bhh,
                                              float* __restrict__ h0, float* __restrict__ c0){
  int b = blockIdx.x, u = threadIdx.x;
  float gi_ = Gd[(size_t)b*G4 + u]        + bih[u]      + bhh[u];
  float gg  = Gd[(size_t)b*G4 + u + 1024] + bih[u+1024] + bhh[u+1024];
  float go  = Gd[(size_t)b*G4 + u + 1536] + bih[u+1536] + bhh[u+1536];
  float cv = fsig(gi_)*ftanhf(gg);
  float hv = fsig(go)*ftanhf(cv);
  h0[b*RNN+u] = hv; c0[b*RNN+u] = cv;
}

// ---------- hoisted gate halves ----------
__global__ __launch_bounds__(256) void k_pre_gemm(const float* __restrict__ h0,
                                                  const float* __restrict__ Wih, const float* __restrict__ Whh,
                                                  const float* __restrict__ bih, const float* __restrict__ bhh,
                                                  float* __restrict__ g1h, float* __restrict__ g2x){
  __shared__ float hL[512][16];
  int m0 = blockIdx.x * 64;
  int tid = threadIdx.x;
  for (int p = 0; p < 2; ++p){
    int k = p*256 + tid;
    for (int n = 0; n < 16; ++n) hL[k][n] = h0[n*512 + k];
  }
  __syncthreads();
  int m_l = tid & 63, ng = tid >> 6;
  int m = m0 + m_l;
  float a1[4] = {0.f,0.f,0.f,0.f}, a2[4] = {0.f,0.f,0.f,0.f};
  const float* w1 = Whh + (size_t)m*512;
  const float* w2 = Wih + (size_t)m*512;
  for (int k = 0; k < 512; k += 4){
    float4 v1 = *(const float4*)&w1[k];
    float4 v2 = *(const float4*)&w2[k];
#pragma unroll
    for (int i=0;i<4;++i){
      int n = ng*4 + i;
      float x0 = hL[k][n], x1 = hL[k+1][n], x2 = hL[k+2][n], x3 = hL[k+3][n];
      a1[i] += v1.x*x0 + v1.y*x1 + v1.z*x2 + v1.w*x3;
      a2[i] += v2.x*x0 + v2.y*x1 + v2.z*x2 + v2.w*x3;
    }
  }
  float bb = bih[m] + bhh[m];
#pragma unroll
  for (int i=0;i<4;++i){
    g1h[(size_t)(ng*4+i)*G4 + m] = a1[i] + bb;
    g2x[(size_t)(ng*4+i)*G4 + m] = a2[i] + bb;
  }
}

// ---------- batched GEMM: G[480][M] = (W[Mx512] @ X[512x480])^T ----------
// MODE 0: X col = embw[gt[bt]];  MODE 1: X col = Xsrc[bt];  MODE 2: like 1 but stores e^{2v}
template<int MODE>
__global__ __launch_bounds__(256) void k_gemm_nt(const float* __restrict__ W,
                                                 const float* __restrict__ Xsrc,
                                                 const int* __restrict__ gt,
                                                 const float* __restrict__ embw,
                                                 float* __restrict__ G, int M){
  __shared__ float As[64][36];
  __shared__ float Bs[32][64];
  int m0 = blockIdx.x * 64, n0 = blockIdx.y * 64;
  int tid = threadIdx.x;
  int tm = tid >> 4, tn = tid & 15;
  float acc[4][4];
#pragma unroll
  for (int i=0;i<4;++i)
#pragma unroll
    for (int j=0;j<4;++j) acc[i][j] = 0.f;

  int sArow = tid >> 2, sAk = (tid & 3)*8;
  const float* arow = W + (size_t)(m0 + sArow)*512 + sAk;
  int n_l = tid & 63, kg = tid >> 6;
  int btc = n0 + n_l; if (btc > 479) btc = 479;
  const float* bcol;
  if (MODE == 0) bcol = embw + (size_t)gt[btc]*512 + kg*8;
  else           bcol = Xsrc + (size_t)btc*512 + kg*8;

  for (int ks = 0; ks < 16; ++ks){
    int k0 = ks*32;
    __syncthreads();
    *(float4*)&As[sArow][sAk]   = *(const float4*)(arow + k0);
    *(float4*)&As[sArow][sAk+4] = *(const float4*)(arow + k0 + 4);
    float4 b0 = *(const float4*)(bcol + k0);
    float4 b1 = *(const float4*)(bcol + k0 + 4);
    Bs[kg*8+0][n_l] = b0.x; Bs[kg*8+1][n_l] = b0.y; Bs[kg*8+2][n_l] = b0.z; Bs[kg*8+3][n_l] = b0.w;
    Bs[kg*8+4][n_l] = b1.x; Bs[kg*8+5][n_l] = b1.y; Bs[kg*8+6][n_l] = b1.z; Bs[kg*8+7][n_l] = b1.w;
    __syncthreads();
#pragma unroll 8
    for (int k = 0; k < 32; ++k){
      float4 bv = *(const float4*)&Bs[k][tn*4];
      float av0 = As[tm*4+0][k], av1 = As[tm*4+1][k], av2 = As[tm*4+2][k], av3 = As[tm*4+3][k];
      acc[0][0] += av0*bv.x; acc[0][1] += av0*bv.y; acc[0][2] += av0*bv.z; acc[0][3] += av0*bv.w;
      acc[1][0] += av1*bv.x; acc[1][1] += av1*bv.y; acc[1][2] += av1*bv.z; acc[1][3] += av1*bv.w;
      acc[2][0] += av2*bv.x; acc[2][1] += av2*bv.y; acc[2][2] += av2*bv.z; acc[2][3] += av2*bv.w;
      acc[3][0] += av3*bv.x; acc[3][1] += av3*bv.y; acc[3][2] += av3*bv.z; acc[3][3] += av3*bv.w;
    }
  }
#pragma unroll
  for (int ni=0; ni<4; ++ni){
    int n = n0 + tn*4 + ni;
    if (n < 480){
#pragma unroll
      for (int mi=0; mi<4; ++mi){
        float v = acc[mi][ni];
        if (MODE == 2) v = __expf(2.0f*v);
        G[(size_t)n*M + m0 + tm*4 + mi] = v;
      }
    }
  }
}

// ---------- LSTM pointwise ----------
__global__ __launch_bounds__(512) void k_lstm1(const float* __restrict__ G1, const float* __restrict__ g1h,
                                               const float* __restrict__ c0,
                                               float* __restrict__ h1, float* __restrict__ c1){
  int bt = blockIdx.x, b = bt / TMAX, u = threadIdx.x;
  float gi_ = G1[(size_t)bt*G4 + u]        + g1h[(size_t)b*G4 + u];
  float gf  = G1[(size_t)bt*G4 + u + 512]  + g1h[(size_t)b*G4 + u + 512];
  float gg  = G1[(size_t)bt*G4 + u + 1024] + g1h[(size_t)b*G4 + u + 1024];
  float go  = G1[(size_t)bt*G4 + u + 1536] + g1h[(size_t)b*G4 + u + 1536];
  float cv = fsig(gf)*c0[b*RNN+u] + fsig(gi_)*ftanhf(gg);
  float hv = fsig(go)*ftanhf(cv);
  h1[(size_t)bt*RNN + u] = hv; c1[(size_t)bt*RNN + u] = cv;
}
__global__ __launch_bounds__(512) void k_lstm2(const float* __restrict__ G2, const float* __restrict__ g2x,
                                               const float* __restrict__ c1, float* __restrict__ h2){
  int bt = blockIdx.x, b = bt / TMAX, u = threadIdx.x;
  float gi_ = G2[(size_t)bt*G4 + u]        + g2x[(size_t)b*G4 + u];
  float gf  = G2[(size_t)bt*G4 + u + 512]  + g2x[(size_t)b*G4 + u + 512];
  float gg  = G2[(size_t)bt*G4 + u + 1024] + g2x[(size_t)b*G4 + u + 1024];
  float go  = G2[(size_t)bt*G4 + u + 1536] + g2x[(size_t)b*G4 + u + 1536];
  float cv = fsig(gf)*c1[(size_t)bt*RNN+u] + fsig(gi_)*ftanhf(gg);
  float hv = fsig(go)*ftanhf(cv);
  h2[(size_t)bt*RNN + u] = hv;
}

// ---------- scores via e^{2f}*e^{2s} factorization (softmax-shift-invariant) ----------
// sc'[t,hw] = -sum_a 2*w_a / (fpe[hw,a]*spe[t,a] + 1)   (== true score minus sum_a w_a)
__global__ __launch_bounds__(512) void k_sc(const float* __restrict__ fpe, const float* __restrict__ spe,
                                            const float* __restrict__ apw, float* __restrict__ sc){
  __shared__ float spL[8][516];
  __shared__ float w2L[512];
  int b = blockIdx.x, hw0 = blockIdx.y * 32, t0 = blockIdx.z * 8;
  int tid = threadIdx.x, lane = tid & 63, wave = tid >> 6;
  for (int i = tid; i < 8*512; i += 512){
    int t = i >> 9, a = i & 511;
    int tg = t0 + t;
    spL[t][a] = (tg < TMAX) ? spe[((size_t)(b*TMAX + tg))*ATTN + a] : 0.f;
  }
  w2L[tid] = -2.0f * apw[tid];
  __syncthreads();
#pragma unroll
  for (int r = 0; r < 4; ++r){
    int row = hw0 + wave*4 + r;
    const float* frow = fpe + ((size_t)b*HWD + row)*ATTN;
    float acc[8];
#pragma unroll
    for (int t=0;t<8;++t) acc[t] = 0.f;
#pragma unroll
    for (int a0 = 0; a0 < 8; ++a0){
      int a = a0*64 + lane;
      float ef = frow[a];
      float w2 = w2L[a];
#pragma unroll
      for (int t=0;t<8;++t){
        float d = __builtin_fmaf(ef, spL[t][a], 1.0f);
        acc[t] = __builtin_fmaf(w2, __builtin_amdgcn_rcpf(d), acc[t]);
      }
    }
#pragma unroll
    for (int t=0;t<8;++t){
      float s = acc[t];
#pragma unroll
      for (int off = 32; off; off >>= 1) s += __shfl_xor(s, off);
      if (lane == 0 && (t0 + t) < TMAX) sc[((size_t)(b*TMAX + t0 + t))*HWD + row] = s;
    }
  }
}

// ---------- softmax ----------
__global__ __launch_bounds__(256) void k_smax(const float* __restrict__ sc, float* __restrict__ attn){
  __shared__ float red[256];
  int bt = blockIdx.x, tid = threadIdx.x;
  float v0 = sc[(size_t)bt*HWD + tid], v1 = sc[(size_t)bt*HWD + tid + 256];
  red[tid] = fmaxf(v0, v1); __syncthreads();
  for (int sd=128; sd; sd>>=1){ if (tid < sd) red[tid] = fmaxf(red[tid], red[tid+sd]); __syncthreads(); }
  float mx = red[0]; __syncthreads();
  float e0 = __expf(v0-mx), e1 = __expf(v1-mx);
  red[tid] = e0+e1; __syncthreads();
  for (int sd=128; sd; sd>>=1){ if (tid < sd) red[tid] += red[tid+sd]; __syncthreads(); }
  float inv = __fdividef(1.0f, red[0]);
  attn[(size_t)bt*HWD + tid]     = e0*inv;
  attn[(size_t)bt*HWD + tid+256] = e1*inv;
}

// ---------- glimpse partials: coalesced bf16 featsP [hw][c], 16 hw-chunks ----------
__global__ __launch_bounds__(512) void k_glimpse(const float* __restrict__ attn, const u16* __restrict__ featsP,
                                                 float* __restrict__ gpart){
  __shared__ float atL[TMAX][32];
  int b = blockIdx.x, hc = blockIdx.y;
  int hw0 = hc*32;
  int tid = threadIdx.x;
  for (int i = tid; i < TMAX*32; i += 512){
    int t = i >> 5, hw = i & 31;
    atL[t][hw] = attn[((size_t)(b*TMAX + t))*HWD + hw0 + hw];
  }
  __syncthreads();
  float acc[TMAX];
#pragma unroll
  for (int t=0;t<TMAX;++t) acc[t] = 0.f;
  const u16* fb = featsP + (size_t)b*PROWS*FEAT;
  for (int hw = 0; hw < 32; ++hw){
    int hwg = hw0 + hw;
    int rowP = hwg + 2*(hwg >> 6) + 67;
    float f = b2f(fb[(size_t)rowP*FEAT + tid]);
#pragma unroll
    for (int t=0;t<TMAX;++t) acc[t] = __builtin_fmaf(f, atL[t][hw], acc[t]);
  }
#pragma unroll
  for (int t = 0; t < TMAX; ++t)
    gpart[(((size_t)hc*BB + b)*TMAX + t)*FEAT + tid] = acc[t];
}

// ---------- logits ----------
__global__ __launch_bounds__(512) void k_logits(const float* __restrict__ gpart,
                                                const float* __restrict__ outw, const float* __restrict__ outb,
                                                float* __restrict__ out){
  __shared__ float gl[512];
  __shared__ float part[4][128];
  int bt = blockIdx.x, b = bt / TMAX, t = bt % TMAX;
  int tid = threadIdx.x;
  float g = 0.f;
#pragma unroll
  for (int p = 0; p < NHC; ++p)
    g += gpart[(((size_t)p*BB + b)*TMAX + t)*FEAT + tid];
  gl[tid] = g;
  __syncthreads();
  int vg = tid >> 7, v = tid & 127;
  int vv = v < VOCABP1 ? v : VOCABP1-1;
  const float* wr = outw + (size_t)vv*512 + vg*128;
  float s = 0.f;
  for (int k = 0; k < 128; k += 4){
    float4 w4 = *(const float4*)&wr[k];
    s += w4.x*gl[vg*128+k] + w4.y*gl[vg*128+k+1] + w4.z*gl[vg*128+k+2] + w4.w*gl[vg*128+k+3];
  }
  part[vg][v] = s;
  __syncthreads();
  if (tid < VOCABP1)
    out[(size_t)bt*VOCABP1 + tid] = part[0][tid] + part[1][tid] + part[2][tid] + part[3][tid] + outb[tid];
}

extern "C" void kernel_launch(void* const* d_in, const int* in_sizes, int n_in,
                              void* d_out, int out_size, void* d_ws, size_t ws_size,
                              hipStream_t stream){
  (void)in_sizes; (void)n_in; (void)out_size; (void)ws_size;
  const float* features = (const float*)d_in[0];
  const float* encoded  = (const float*)d_in[1];
  const float* embed_w  = (const float*)d_in[2];
  const float* dec_Wih  = (const float*)d_in[3];
  const float* dec_bih  = (const float*)d_in[5];
  const float* dec_bhh  = (const float*)d_in[6];
  const float* att_Wih  = (const float*)d_in[7];
  const float* att_Whh  = (const float*)d_in[8];
  const float* att_bih  = (const float*)d_in[9];
  const float* att_bhh  = (const float*)d_in[10];
  const float* fconv_w  = (const float*)d_in[11];
  const float* fconv_b  = (const float*)d_in[12];
  const float* scw      = (const float*)d_in[13];
  const float* apw      = (const float*)d_in[14];
  const float* outw     = (const float*)d_in[15];
  const float* outb     = (const float*)d_in[16];
  const int* gt         = (const int*)d_in[17];

  char* ws = (char*)d_ws;
  u16*  featsP = (u16*)(ws + 0);            // 10,813,440
  u16*  wB     = (u16*)(ws + 10813440);     //  4,718,592
  float* fpe   = (float*)(ws + 15532032);   // 16,777,216 (reused as gpart after k_sc)
  float* Gd    = (float*)(ws + 32309248);   //    131,072
  float* h0    = (float*)(ws + 32440320);   //     32,768
  float* c0    = (float*)(ws + 32473088);   //     32,768
  float* g1h   = (float*)(ws + 32505856);   //    131,072
  float* g2x   = (float*)(ws + 32636928);   //    131,072
  float* G1    = (float*)(ws + 32768000);   //  3,932,160  (reused for G2)
  float* h1    = (float*)(ws + 36700160);   //    983,040
  float* c1    = (float*)(ws + 37683200);   //    983,040
  float* h2    = (float*)(ws + 38666240);   //    983,040
  float* spe   = (float*)(ws + 39649280);   //    983,040
  float* sc    = (float*)(ws + 40632320);   //    983,040
  float* attn  = (float*)(ws + 41615360);   //    983,040 -> total 42,598,400 B
  float* gpart = fpe;                       // 16 chunks x 16 b x 30 t x 512 c x 4B = 15,728,640 <= 16.7MB

  hipMemsetAsync(featsP, 0, 10813440, stream);
  k_tfeat<<<dim3(8,8,16), 256, 0, stream>>>(features, featsP);
  k_twt<<<dim3(9216), 256, 0, stream>>>(fconv_w, wB);
  k_conv<<<dim3(64,8), 256, 0, stream>>>(featsP, wB, fconv_b, fpe);

  k_dec_gemm<<<dim3(32), 256, 0, stream>>>(encoded, dec_Wih, Gd);
  k_h0c0<<<dim3(16), 512, 0, stream>>>(Gd, dec_bih, dec_bhh, h0, c0);
  k_pre_gemm<<<dim3(32), 256, 0, stream>>>(h0, att_Wih, att_Whh, att_bih, att_bhh, g1h, g2x);

  k_gemm_nt<0><<<dim3(32,8), 256, 0, stream>>>(att_Wih, nullptr, gt, embed_w, G1, G4);
  k_lstm1<<<dim3(480), 512, 0, stream>>>(G1, g1h, c0, h1, c1);
  k_gemm_nt<1><<<dim3(32,8), 256, 0, stream>>>(att_Whh, h1, nullptr, nullptr, G1, G4);
  k_lstm2<<<dim3(480), 512, 0, stream>>>(G1, g2x, c1, h2);
  k_gemm_nt<2><<<dim3(8,8), 256, 0, stream>>>(scw, h2, nullptr, nullptr, spe, ATTN);

  k_sc<<<dim3(16,16,4), 512, 0, stream>>>(fpe, spe, apw, sc);
  k_smax<<<dim3(480), 256, 0, stream>>>(sc, attn);
  k_glimpse<<<dim3(16,NHC), 512, 0, stream>>>(attn, featsP, gpart);
  k_logits<<<dim3(480), 512, 0, stream>>>(gpart, outw, outb, (float*)d_out);
}

// Round 9
// 365.505 us; speedup vs baseline: 4.1989x; 1.1700x over previous
//
#include <hip/hip_runtime.h>
#include <hip/hip_bf16.h>
#include <stdint.h>

#define BB 16
#define TMAX 30
#define FEAT 512
#define RNN 512
#define ATTN 512
#define VOCABP1 111
#define HWD 512
#define PH 10
#define PW 66
#define PROWS 660
#define G4 2048
#define NHC 16
#define LSTR 40   // padded LDS row stride (u16) for MFMA tiles

typedef unsigned short u16;
typedef __attribute__((ext_vector_type(8))) unsigned short us8v;
typedef __attribute__((ext_vector_type(8))) short short8;
typedef __attribute__((ext_vector_type(4))) float f32x4;

__device__ __forceinline__ float b2f(u16 b){
  unsigned int u = ((unsigned int)b) << 16;
  return __builtin_bit_cast(float, u);
}
__device__ __forceinline__ u16 f2b(float x){   // RNE
  unsigned int u = __builtin_bit_cast(unsigned int, x);
  unsigned int r = u + 0x7FFFu + ((u >> 16) & 1u);
  return (u16)(r >> 16);
}
__device__ __forceinline__ float fsig(float x){ return __fdividef(1.0f, 1.0f + __expf(-x)); }
__device__ __forceinline__ float ftanhf(float x){ return 1.0f - __fdividef(2.0f, __expf(2.0f*x) + 1.0f); }

// ---------- fused prep: tfeat transpose+pad, conv-wt transpose, bf16 converts, pad-zero ----------
__global__ __launch_bounds__(256) void k_prep(const float* __restrict__ feats, const float* __restrict__ fconv_w,
                                              const float* __restrict__ att_Wih, const float* __restrict__ att_Whh,
                                              const float* __restrict__ scw, const float* __restrict__ embw,
                                              u16* __restrict__ featsP, u16* __restrict__ wB,
                                              u16* __restrict__ wAih, u16* __restrict__ wAhh,
                                              u16* __restrict__ wScw, u16* __restrict__ wEmb){
  __shared__ float tile[64*65];
  int blk = blockIdx.x, tid = threadIdx.x;
  if (blk < 1024){
    // region 0: features [B,C,HW] -> padded bf16 [B,PROWS,C]
    int hwb = blk & 7, cb = (blk >> 3) & 7, b = blk >> 6;
    int c0 = cb*64, hw0 = hwb*64;
    int tx = tid & 63, ty = tid >> 6;
#pragma unroll
    for (int r = 0; r < 16; ++r){
      int cl = ty*16 + r;
      tile[cl*65 + tx] = feats[((size_t)(b*FEAT + c0 + cl))*HWD + hw0 + tx];
    }
    __syncthreads();
#pragma unroll
    for (int r = 0; r < 16; ++r){
      int hwl = ty*16 + r;
      int hw = hw0 + hwl;
      int rowP = hw + 2*(hw >> 6) + 67;
      featsP[((size_t)b*PROWS + rowP)*FEAT + c0 + tx] = f2b(tile[tx*65 + hwl]);
    }
  } else if (blk < 2048){
    // region 1: conv weights [O,C,3,3] -> bf16 wB[k9][o][c]
    int idx = (blk - 1024)*256 + tid;
#pragma unroll
    for (int j = 0; j < 9; ++j){
      int e = j*262144 + idx;
      int c = e & 511, n = (e >> 9) & 511, k9 = e >> 18;
      wB[e] = f2b(fconv_w[((size_t)(n*512 + c))*9 + k9]);
    }
  } else if (blk < 2560){
    // region 2: bf16 converts of att_Wih / att_Whh / scw / embw
    const int T2 = 1048576 + 1048576 + 262144 + VOCABP1*512;  // 2,416,000? compute below
    int gtid = (blk - 2048)*256 + tid;     // 131072 threads
    for (int e = gtid; e < T2; e += 131072){
      if (e < 1048576)            wAih[e]           = f2b(att_Wih[e]);
      else if (e < 2097152)       wAhh[e - 1048576] = f2b(att_Whh[e - 1048576]);
      else if (e < 2359296)       wScw[e - 2097152] = f2b(scw[e - 2097152]);
      else                        wEmb[e - 2359296] = f2b(embw[e - 2359296]);
    }
  } else {
    // region 3: zero featsP border rows (148 per b)
    int blkl = blk - 2560;
    for (int r = blkl; r < 148*BB; r += 128){
      int b = r / 148, j = r % 148;
      int rowP;
      if (j < 66) rowP = j;
      else if (j < 132) rowP = 594 + (j - 66);
      else if (j < 140) rowP = (j - 132 + 1)*66;
      else rowP = (j - 140 + 1)*66 + 65;
      ((unsigned int*)&featsP[((size_t)b*PROWS + rowP)*FEAT])[tid] = 0u;
    }
  }
}

// ---------- conv as implicit-im2col MFMA bf16 GEMM; padded LDS; epilogue e^{2v} ----------
__global__ __launch_bounds__(256) void k_conv(const u16* __restrict__ featsP, const u16* __restrict__ wB,
                                              const float* __restrict__ bias, float* __restrict__ fpe){
  __shared__ __align__(16) u16 As[128*LSTR];
  __shared__ __align__(16) u16 Bs[64*LSTR];
  int m0 = blockIdx.x * 128, n0 = blockIdx.y * 64;
  int tid = threadIdx.x, lane = tid & 63, wave = tid >> 6;
  int wm = wave >> 1, wn = wave & 1;

  int kk = (lane & 3) * 8;
  int rA0 = 32*wave + (lane >> 2);
  int rA1 = rA0 + 16;
  int mA0 = m0 + rA0, mA1 = m0 + rA1;
  long baseA0 = ((long)((mA0 >> 9)*PH + ((mA0 >> 6) & 7) + 1)*PW + (mA0 & 63) + 1)*FEAT + kk;
  long baseA1 = ((long)((mA1 >> 9)*PH + ((mA1 >> 6) & 7) + 1)*PW + (mA1 & 63) + 1)*FEAT + kk;
  int nloc = 16*wave + (lane >> 2);
  long baseB = (long)(n0 + nloc)*512 + kk;

  f32x4 acc[4][2];
#pragma unroll
  for (int i=0;i<4;++i)
#pragma unroll
    for (int j=0;j<2;++j) acc[i][j] = (f32x4){0.f,0.f,0.f,0.f};

  int arow = wm*64 + (lane & 15);
  int akc  = (lane >> 4) * 8;
  int brow = wn*32 + (lane & 15);

  us8v a0c, a1c, bc;
  {
    long dA = (long)(-1*PW - 1)*FEAT;
    a0c = *(const us8v*)(featsP + baseA0 + dA);
    a1c = *(const us8v*)(featsP + baseA1 + dA);
    bc  = *(const us8v*)(wB + baseB);
  }

  for (int ks = 0; ks < 144; ++ks){
    __syncthreads();
    *(us8v*)&As[rA0*LSTR + kk] = a0c;
    *(us8v*)&As[rA1*LSTR + kk] = a1c;
    *(us8v*)&Bs[nloc*LSTR + kk] = bc;
    __syncthreads();
    if (ks < 143){
      int kn = ks + 1;
      int o = kn >> 4;
      int c0 = (kn & 15) << 5;
      int dy = o/3 - 1, dx = o - (o/3)*3 - 1;
      long dA = (long)(dy*PW + dx)*FEAT + c0;
      long dB = (long)o*(512*512) + c0;
      a0c = *(const us8v*)(featsP + baseA0 + dA);
      a1c = *(const us8v*)(featsP + baseA1 + dA);
      bc  = *(const us8v*)(wB + baseB + dB);
    }
    short8 a[4], bfr[2];
#pragma unroll
    for (int mt=0; mt<4; ++mt) a[mt] = *(const short8*)&As[(arow + mt*16)*LSTR + akc];
#pragma unroll
    for (int nt=0; nt<2; ++nt) bfr[nt] = *(const short8*)&Bs[(brow + nt*16)*LSTR + akc];
#pragma unroll
    for (int mt=0; mt<4; ++mt)
#pragma unroll
      for (int nt=0; nt<2; ++nt)
        acc[mt][nt] = __builtin_amdgcn_mfma_f32_16x16x32_bf16(a[mt], bfr[nt], acc[mt][nt], 0, 0, 0);
  }
  int col = lane & 15;
  int rbase = (lane >> 4) * 4;
#pragma unroll
  for (int mt=0; mt<4; ++mt){
#pragma unroll
    for (int nt=0; nt<2; ++nt){
      int gn = n0 + wn*32 + nt*16 + col;
      float bv = bias[gn];
#pragma unroll
      for (int r=0; r<4; ++r){
        int gm = m0 + wm*64 + mt*16 + rbase + r;
        fpe[(size_t)gm*ATTN + gn] = __expf(2.0f*(acc[mt][nt][r] + bv));
      }
    }
  }
}

// ---------- MFMA bf16 GEMM: G[480][M] = (A[Mx512] @ X^T)^T ----------
// MODE 0: X row for bt = wEmb[gt[bt]]; MODE 1: X row = X[bt]. EXPOUT: store e^{2v}.
template<int MODE, bool EXPOUT>
__global__ __launch_bounds__(256) void k_gemm_mfma(const u16* __restrict__ A, const u16* __restrict__ X,
                                                   const int* __restrict__ gt, float* __restrict__ G, int M){
  __shared__ __align__(16) u16 As[128*LSTR];
  __shared__ __align__(16) u16 Bs[64*LSTR];
  int m0 = blockIdx.x * 128, n0 = blockIdx.y * 64;
  int tid = threadIdx.x, lane = tid & 63, wave = tid >> 6;
  int wm = wave >> 1, wn = wave & 1;

  int kk = (lane & 3) * 8;
  int rA0 = 32*wave + (lane >> 2);
  int rA1 = rA0 + 16;
  const u16* aptr0 = A + (size_t)(m0 + rA0)*512 + kk;
  const u16* aptr1 = A + (size_t)(m0 + rA1)*512 + kk;
  int nloc = 16*wave + (lane >> 2);
  int btc = n0 + nloc; if (btc > 479) btc = 479;
  const u16* bptr;
  if (MODE == 0) bptr = X + (size_t)gt[btc]*512 + kk;
  else           bptr = X + (size_t)btc*512 + kk;

  f32x4 acc[4][2];
#pragma unroll
  for (int i=0;i<4;++i)
#pragma unroll
    for (int j=0;j<2;++j) acc[i][j] = (f32x4){0.f,0.f,0.f,0.f};

  int arow = wm*64 + (lane & 15);
  int akc  = (lane >> 4) * 8;
  int brow = wn*32 + (lane & 15);

  us8v a0c = *(const us8v*)aptr0;
  us8v a1c = *(const us8v*)aptr1;
  us8v bc  = *(const us8v*)bptr;

  for (int ks = 0; ks < 16; ++ks){
    __syncthreads();
    *(us8v*)&As[rA0*LSTR + kk] = a0c;
    *(us8v*)&As[rA1*LSTR + kk] = a1c;
    *(us8v*)&Bs[nloc*LSTR + kk] = bc;
    __syncthreads();
    if (ks < 15){
      int off = (ks + 1)*32;
      a0c = *(const us8v*)(aptr0 + off);
      a1c = *(const us8v*)(aptr1 + off);
      bc  = *(const us8v*)(bptr + off);
    }
    short8 a[4], bfr[2];
#pragma unroll
    for (int mt=0; mt<4; ++mt) a[mt] = *(const short8*)&As[(arow + mt*16)*LSTR + akc];
#pragma unroll
    for (int nt=0; nt<2; ++nt) bfr[nt] = *(const short8*)&Bs[(brow + nt*16)*LSTR + akc];
#pragma unroll
    for (int mt=0; mt<4; ++mt)
#pragma unroll
      for (int nt=0; nt<2; ++nt)
        acc[mt][nt] = __builtin_amdgcn_mfma_f32_16x16x32_bf16(a[mt], bfr[nt], acc[mt][nt], 0, 0, 0);
  }
  int col = lane & 15;
  int rbase = (lane >> 4) * 4;
#pragma unroll
  for (int mt=0; mt<4; ++mt){
#pragma unroll
    for (int nt=0; nt<2; ++nt){
      int gbt = n0 + wn*32 + nt*16 + col;
      if (gbt < 480){
#pragma unroll
        for (int r=0; r<4; ++r){
          int gm = m0 + wm*64 + mt*16 + rbase + r;
          float v = acc[mt][nt][r];
          if (EXPOUT) v = __expf(2.0f*v);
          G[(size_t)gbt*M + gm] = v;
        }
      }
    }
  }
}

// ---------- decoder gates GEMM: Gd[16][2048] (fp32) ----------
__global__ __launch_bounds__(256) void k_dec_gemm(const float* __restrict__ encoded, const float* __restrict__ Wih,
                                                  float* __restrict__ Gd){
  __shared__ float encL[512][16];
  int m0 = blockIdx.x * 64;
  int tid = threadIdx.x;
  for (int p = 0; p < 2; ++p){
    int k = p*256 + tid;
    for (int n = 0; n < 16; ++n) encL[k][n] = encoded[n*512 + k];
  }
  __syncthreads();
  int m_l = tid & 63, ng = tid >> 6;
  float acc[4] = {0.f,0.f,0.f,0.f};
  const float* wrow = Wih + (size_t)(m0 + m_l)*512;
  for (int k = 0; k < 512; k += 4){
    float4 w4 = *(const float4*)&wrow[k];
#pragma unroll
    for (int i=0;i<4;++i){
      int n = ng*4 + i;
      acc[i] += w4.x*encL[k][n] + w4.y*encL[k+1][n] + w4.z*encL[k+2][n] + w4.w*encL[k+3][n];
    }
  }
#pragma unroll
  for (int i=0;i<4;++i) Gd[(size_t)(ng*4+i)*G4 + m0 + m_l] = acc[i];
}

// ---------- hoisted gate halves; h0 recomputed inline from Gd ----------
__global__ __launch_bounds__(256) void k_pre_gemm(const float* __restrict__ Gd,
                                                  const float* __restrict__ dbih, const float* __restrict__ dbhh,
                                                  const float* __restrict__ Wih, const float* __restrict__ Whh,
                                                  const float* __restrict__ bih, const float* __restrict__ bhh,
                                                  float* __restrict__ g1h, float* __restrict__ g2x){
  __shared__ float hL[512][16];
  int m0 = blockIdx.x * 64;
  int tid = threadIdx.x;
  for (int i = tid; i < 8192; i += 256){
    int k = i >> 4, n = i & 15;
    float gi = Gd[(size_t)n*G4 + k]        + dbih[k]      + dbhh[k];
    float gg = Gd[(size_t)n*G4 + k + 1024] + dbih[k+1024] + dbhh[k+1024];
    float go = Gd[(size_t)n*G4 + k + 1536] + dbih[k+1536] + dbhh[k+1536];
    float cv = fsig(gi)*ftanhf(gg);
    hL[k][n] = fsig(go)*ftanhf(cv);
  }
  __syncthreads();
  int m_l = tid & 63, ng = tid >> 6;
  int m = m0 + m_l;
  float a1[4] = {0.f,0.f,0.f,0.f}, a2[4] = {0.f,0.f,0.f,0.f};
  const float* w1 = Whh + (size_t)m*512;
  const float* w2 = Wih + (size_t)m*512;
  for (int k = 0; k < 512; k += 4){
    float4 v1 = *(const float4*)&w1[k];
    float4 v2 = *(const float4*)&w2[k];
#pragma unroll
    for (int i=0;i<4;++i){
      int n = ng*4 + i;
      float x0 = hL[k][n], x1 = hL[k+1][n], x2 = hL[k+2][n], x3 = hL[k+3][n];
      a1[i] += v1.x*x0 + v1.y*x1 + v1.z*x2 + v1.w*x3;
      a2[i] += v2.x*x0 + v2.y*x1 + v2.z*x2 + v2.w*x3;
    }
  }
  float bb = bih[m] + bhh[m];
#pragma unroll
  for (int i=0;i<4;++i){
    g1h[(size_t)(ng*4+i)*G4 + m] = a1[i] + bb;
    g2x[(size_t)(ng*4+i)*G4 + m] = a2[i] + bb;
  }
}

// ---------- LSTM pointwise (c0 inline from Gd); h out in bf16 ----------
__global__ __launch_bounds__(512) void k_lstm1(const float* __restrict__ G1, const float* __restrict__ g1h,
                                               const float* __restrict__ Gd,
                                               const float* __restrict__ dbih, const float* __restrict__ dbhh,
                                               u16* __restrict__ h1b, float* __restrict__ c1){
  int bt = blockIdx.x, b = bt / TMAX, u = threadIdx.x;
  float dgi = Gd[(size_t)b*G4 + u]        + dbih[u]      + dbhh[u];
  float dgg = Gd[(size_t)b*G4 + u + 1024] + dbih[u+1024] + dbhh[u+1024];
  float c0v = fsig(dgi)*ftanhf(dgg);
  float gi_ = G1[(size_t)bt*G4 + u]        + g1h[(size_t)b*G4 + u];
  float gf  = G1[(size_t)bt*G4 + u + 512]  + g1h[(size_t)b*G4 + u + 512];
  float gg  = G1[(size_t)bt*G4 + u + 1024] + g1h[(size_t)b*G4 + u + 1024];
  float go  = G1[(size_t)bt*G4 + u + 1536] + g1h[(size_t)b*G4 + u + 1536];
  float cv = fsig(gf)*c0v + fsig(gi_)*ftanhf(gg);
  float hv = fsig(go)*ftanhf(cv);
  h1b[(size_t)bt*RNN + u] = f2b(hv); c1[(size_t)bt*RNN + u] = cv;
}
__global__ __launch_bounds__(512) void k_lstm2(const float* __restrict__ G2, const float* __restrict__ g2x,
                                               const float* __restrict__ c1, u16* __restrict__ h2b){
  int bt = blockIdx.x, b = bt / TMAX, u = threadIdx.x;
  float gi_ = G2[(size_t)bt*G4 + u]        + g2x[(size_t)b*G4 + u];
  float gf  = G2[(size_t)bt*G4 + u + 512]  + g2x[(size_t)b*G4 + u + 512];
  float gg  = G2[(size_t)bt*G4 + u + 1024] + g2x[(size_t)b*G4 + u + 1024];
  float go  = G2[(size_t)bt*G4 + u + 1536] + g2x[(size_t)b*G4 + u + 1536];
  float cv = fsig(gf)*c1[(size_t)bt*RNN+u] + fsig(gi_)*ftanhf(gg);
  float hv = fsig(go)*ftanhf(cv);
  h2b[(size_t)bt*RNN + u] = f2b(hv);
}

// ---------- scores via e^{2f}*e^{2s} factorization ----------
__global__ __launch_bounds__(512) void k_sc(const float* __restrict__ fpe, const float* __restrict__ spe,
                                            const float* __restrict__ apw, float* __restrict__ sc){
  __shared__ float spL[8][516];
  __shared__ float w2L[512];
  int b = blockIdx.x, hw0 = blockIdx.y * 32, t0 = blockIdx.z * 8;
  int tid = threadIdx.x, lane = tid & 63, wave = tid >> 6;
  for (int i = tid; i < 8*512; i += 512){
    int t = i >> 9, a = i & 511;
    int tg = t0 + t;
    spL[t][a] = (tg < TMAX) ? spe[((size_t)(b*TMAX + tg))*ATTN + a] : 0.f;
  }
  w2L[tid] = -2.0f * apw[tid];
  __syncthreads();
#pragma unroll
  for (int r = 0; r < 4; ++r){
    int row = hw0 + wave*4 + r;
    const float* frow = fpe + ((size_t)b*HWD + row)*ATTN;
    float acc[8];
#pragma unroll
    for (int t=0;t<8;++t) acc[t] = 0.f;
#pragma unroll
    for (int a0 = 0; a0 < 8; ++a0){
      int a = a0*64 + lane;
      float ef = frow[a];
      float w2 = w2L[a];
#pragma unroll
      for (int t=0;t<8;++t){
        float d = __builtin_fmaf(ef, spL[t][a], 1.0f);
        acc[t] = __builtin_fmaf(w2, __builtin_amdgcn_rcpf(d), acc[t]);
      }
    }
#pragma unroll
    for (int t=0;t<8;++t){
      float s = acc[t];
#pragma unroll
      for (int off = 32; off; off >>= 1) s += __shfl_xor(s, off);
      if (lane == 0 && (t0 + t) < TMAX) sc[((size_t)(b*TMAX + t0 + t))*HWD + row] = s;
    }
  }
}

// ---------- softmax ----------
__global__ __launch_bounds__(256) void k_smax(const float* __restrict__ sc, float* __restrict__ attn){
  __shared__ float red[256];
  int bt = blockIdx.x, tid = threadIdx.x;
  float v0 = sc[(size_t)bt*HWD + tid], v1 = sc[(size_t)bt*HWD + tid + 256];
  red[tid] = fmaxf(v0, v1); __syncthreads();
  for (int sd=128; sd; sd>>=1){ if (tid < sd) red[tid] = fmaxf(red[tid], red[tid+sd]); __syncthreads(); }
  float mx = red[0]; __syncthreads();
  float e0 = __expf(v0-mx), e1 = __expf(v1-mx);
  red[tid] = e0+e1; __syncthreads();
  for (int sd=128; sd; sd>>=1){ if (tid < sd) red[tid] += red[tid+sd]; __syncthreads(); }
  float inv = __fdividef(1.0f, red[0]);
  attn[(size_t)bt*HWD + tid]     = e0*inv;
  attn[(size_t)bt*HWD + tid+256] = e1*inv;
}

// ---------- glimpse partials: coalesced bf16 featsP ----------
__global__ __launch_bounds__(512) void k_glimpse(const float* __restrict__ attn, const u16* __restrict__ featsP,
                                                 float* __restrict__ gpart){
  __shared__ float atL[TMAX][32];
  int b = blockIdx.x, hc = blockIdx.y;
  int hw0 = hc*32;
  int tid = threadIdx.x;
  for (int i = tid; i < TMAX*32; i += 512){
    int t = i >> 5, hw = i & 31;
    atL[t][hw] = attn[((size_t)(b*TMAX + t))*HWD + hw0 + hw];
  }
  __syncthreads();
  float acc[TMAX];
#pragma unroll
  for (int t=0;t<TMAX;++t) acc[t] = 0.f;
  const u16* fb = featsP + (size_t)b*PROWS*FEAT;
  for (int hw = 0; hw < 32; ++hw){
    int hwg = hw0 + hw;
    int rowP = hwg + 2*(hwg >> 6) + 67;
    float f = b2f(fb[(size_t)rowP*FEAT + tid]);
#pragma unroll
    for (int t=0;t<TMAX;++t) acc[t] = __builtin_fmaf(f, atL[t][hw], acc[t]);
  }
#pragma unroll
  for (int t = 0; t < TMAX; ++t)
    gpart[(((size_t)hc*BB + b)*TMAX + t)*FEAT + tid] = acc[t];
}

// ---------- logits ----------
__global__ __launch_bounds__(512) void k_logits(const float* __restrict__ gpart,
                                                const float* __restrict__ outw, const float* __restrict__ outb,
                                                float* __restrict__ out){
  __shared__ float gl[512];
  __shared__ float part[4][128];
  int bt = blockIdx.x, b = bt / TMAX, t = bt % TMAX;
  int tid = threadIdx.x;
  float g = 0.f;
#pragma unroll
  for (int p = 0; p < NHC; ++p)
    g += gpart[(((size_t)p*BB + b)*TMAX + t)*FEAT + tid];
  gl[tid] = g;
  __syncthreads();
  int vg = tid >> 7, v = tid & 127;
  int vv = v < VOCABP1 ? v : VOCABP1-1;
  const float* wr = outw + (size_t)vv*512 + vg*128;
  float s = 0.f;
  for (int k = 0; k < 128; k += 4){
    float4 w4 = *(const float4*)&wr[k];
    s += w4.x*gl[vg*128+k] + w4.y*gl[vg*128+k+1] + w4.z*gl[vg*128+k+2] + w4.w*gl[vg*128+k+3];
  }
  part[vg][v] = s;
  __syncthreads();
  if (tid < VOCABP1)
    out[(size_t)bt*VOCABP1 + tid] = part[0][tid] + part[1][tid] + part[2][tid] + part[3][tid] + outb[tid];
}

extern "C" void kernel_launch(void* const* d_in, const int* in_sizes, int n_in,
                              void* d_out, int out_size, void* d_ws, size_t ws_size,
                              hipStream_t stream){
  (void)in_sizes; (void)n_in; (void)out_size; (void)ws_size;
  const float* features = (const float*)d_in[0];
  const float* encoded  = (const float*)d_in[1];
  const float* embed_w  = (const float*)d_in[2];
  const float* dec_Wih  = (const float*)d_in[3];
  const float* dec_bih  = (const float*)d_in[5];
  const float* dec_bhh  = (const float*)d_in[6];
  const float* att_Wih  = (const float*)d_in[7];
  const float* att_Whh  = (const float*)d_in[8];
  const float* att_bih  = (const float*)d_in[9];
  const float* att_bhh  = (const float*)d_in[10];
  const float* fconv_w  = (const float*)d_in[11];
  const float* fconv_b  = (const float*)d_in[12];
  const float* scw      = (const float*)d_in[13];
  const float* apw      = (const float*)d_in[14];
  const float* outw     = (const float*)d_in[15];
  const float* outb     = (const float*)d_in[16];
  const int* gt         = (const int*)d_in[17];

  char* ws = (char*)d_ws;
  u16*  featsP = (u16*)(ws + 0);            // 10,813,440
  u16*  wB     = (u16*)(ws + 10813440);     //  4,718,592
  float* fpe   = (float*)(ws + 15532032);   // 16,777,216 (reused as gpart)
  u16*  wAih   = (u16*)(ws + 32309248);     //  2,097,152
  u16*  wAhh   = (u16*)(ws + 34406400);     //  2,097,152
  u16*  wScw   = (u16*)(ws + 36503552);     //    524,288
  u16*  wEmb   = (u16*)(ws + 37027840);     //    113,664
  float* Gd    = (float*)(ws + 37141504);   //    131,072
  float* g1h   = (float*)(ws + 37272576);   //    131,072
  float* g2x   = (float*)(ws + 37403648);   //    131,072
  float* G1    = (float*)(ws + 37534720);   //  3,932,160
  u16*  h1b    = (u16*)(ws + 41466880);     //    491,520
  float* c1    = (float*)(ws + 41958400);   //    983,040
  u16*  h2b    = (u16*)(ws + 42941440);     //    491,520
  float* spe   = (float*)(ws + 43432960);   //    983,040
  float* sc    = (float*)(ws + 44416000);   //    983,040
  float* attn  = (float*)(ws + 45399040);   //    983,040 -> total 46,382,080 B
  float* gpart = fpe;

  k_prep<<<dim3(2688), 256, 0, stream>>>(features, fconv_w, att_Wih, att_Whh, scw, embed_w,
                                         featsP, wB, wAih, wAhh, wScw, wEmb);
  k_conv<<<dim3(64,8), 256, 0, stream>>>(featsP, wB, fconv_b, fpe);

  k_dec_gemm<<<dim3(32), 256, 0, stream>>>(encoded, dec_Wih, Gd);
  k_pre_gemm<<<dim3(32), 256, 0, stream>>>(Gd, dec_bih, dec_bhh, att_Wih, att_Whh, att_bih, att_bhh, g1h, g2x);

  k_gemm_mfma<0,false><<<dim3(16,8), 256, 0, stream>>>(wAih, wEmb, gt, G1, G4);
  k_lstm1<<<dim3(480), 512, 0, stream>>>(G1, g1h, Gd, dec_bih, dec_bhh, h1b, c1);
  k_gemm_mfma<1,false><<<dim3(16,8), 256, 0, stream>>>(wAhh, h1b, nullptr, G1, G4);
  k_lstm2<<<dim3(480), 512, 0, stream>>>(G1, g2x, c1, h2b);
  k_gemm_mfma<1,true><<<dim3(4,8), 256, 0, stream>>>(wScw, h2b, nullptr, spe, ATTN);

  k_sc<<<dim3(16,16,4), 512, 0, stream>>>(fpe, spe, apw, sc);
  k_smax<<<dim3(480), 256, 0, stream>>>(sc, attn);
  k_glimpse<<<dim3(16,NHC), 512, 0, stream>>>(attn, featsP, gpart);
  k_logits<<<dim3(480), 512, 0, stream>>>(gpart, outw, outb, (float*)d_out);
}